// Round 1
// baseline (2749.890 us; speedup 1.0000x reference)
//
#include <hip/hip_runtime.h>
#include <hip/hip_bf16.h>
#include <math.h>

#define G 4
#define BZ 4
#define LSEQ 2048
#define DM 512
#define DI 1024
#define DS 16
#define NROW (G*BZ*LSEQ)   /* 32768 */
#define RB (BZ*LSEQ)       /* 8192 rows per ssm-block */

typedef unsigned short u16;
typedef unsigned int u32;

__device__ __forceinline__ float bf2f(u16 v){ return __uint_as_float(((u32)v) << 16); }
__device__ __forceinline__ u16 f2bf(float f){
    u32 u = __float_as_uint(f);
    u32 r = (u + 0x7FFFu + ((u >> 16) & 1u)) >> 16;   // RNE
    return (u16)r;
}
__device__ __forceinline__ float sigmoidf_(float x){ return 1.0f / (1.0f + __expf(-x)); }
__device__ __forceinline__ float siluf_(float x){ return x / (1.0f + __expf(-x)); }
__device__ __forceinline__ float softplusf_(float v){
    return fmaxf(v, 0.0f) + log1pf(__expf(-fabsf(v)));
}
__device__ __forceinline__ uint2 pack4bf(float a, float b, float c, float d){
    uint2 p;
    p.x = (u32)f2bf(a) | ((u32)f2bf(b) << 16);
    p.y = (u32)f2bf(c) | ((u32)f2bf(d) << 16);
    return p;
}

// ---------------------------------------------------------------- K0: xproj_w [g][d][33] -> WT [g][o][d]
__global__ void k0_transpose_xproj(const float* __restrict__ xw, float* __restrict__ wt){
    int i = blockIdx.x * 256 + threadIdx.x;
    if (i >= G * 33 * DI) return;
    int d  = i & (DI - 1);
    int go = i >> 10;          // g*33 + o
    int o  = go % 33;
    int g  = go / 33;
    wt[i] = xw[((size_t)g * DI + d) * 33 + o];
}

// ---------------------------------------------------------------- K1: xz = Xin[g] @ in_w[g]; split -> xcraw(bf16), silu(z)(bf16)
__global__ __launch_bounds__(256) void k1_gemm_in(const float* __restrict__ X,
        const float* __restrict__ W_all, u16* __restrict__ xcraw, u16* __restrict__ siluz)
{
    const int g    = blockIdx.z;
    const int n0   = blockIdx.x * 64;
    const int row0 = blockIdx.y * 64;
    const float* W = W_all + (size_t)g * DM * (2 * DI);
    __shared__ float As[16][68];
    __shared__ float Bs[16][68];
    const int tid = threadIdx.x;
    const int tx = tid & 15, ty = tid >> 4;
    float acc[4][4] = {};
    // A staging coords
    const int a_row = tid >> 2;            // 0..63
    const int a_k   = (tid & 3) * 4;       // 0,4,8,12
    {
        int r = row0 + a_row;
        int b = r >> 11, l = r & 2047;
        int lsrc = (g & 1) ? (2047 - l) : l;
        const float* arow_ptr = X + ((size_t)(b * LSEQ + lsrc)) * DM;
        const int b_k = tid >> 4;          // 0..15
        const int b_n = (tid & 15) * 4;
        for (int k0 = 0; k0 < DM; k0 += 16){
            float4 av = *(const float4*)(arow_ptr + k0 + a_k);
            float4 bv = *(const float4*)(W + (size_t)(k0 + b_k) * (2 * DI) + n0 + b_n);
            __syncthreads();
            As[a_k + 0][a_row] = av.x; As[a_k + 1][a_row] = av.y;
            As[a_k + 2][a_row] = av.z; As[a_k + 3][a_row] = av.w;
            *(float4*)&Bs[b_k][b_n] = bv;
            __syncthreads();
            #pragma unroll
            for (int kk = 0; kk < 16; ++kk){
                const float4 a4 = *(const float4*)&As[kk][ty * 4];
                const float4 b4 = *(const float4*)&Bs[kk][tx * 4];
                float ar[4] = {a4.x, a4.y, a4.z, a4.w};
                float br[4] = {b4.x, b4.y, b4.z, b4.w};
                #pragma unroll
                for (int i = 0; i < 4; ++i)
                    #pragma unroll
                    for (int j = 0; j < 4; ++j)
                        acc[i][j] = fmaf(ar[i], br[j], acc[i][j]);
            }
        }
    }
    const bool is_z = (n0 >= DI);
    const int colb = n0 + tx * 4 - (is_z ? DI : 0);
    #pragma unroll
    for (int i = 0; i < 4; ++i){
        int rr = row0 + ty * 4 + i;
        int bb = rr >> 11, ll = rr & 2047;
        size_t obase = ((size_t)(g * BZ + bb) * LSEQ + ll) * DI + colb;
        float v0 = acc[i][0], v1 = acc[i][1], v2 = acc[i][2], v3 = acc[i][3];
        if (is_z){ v0 = siluf_(v0); v1 = siluf_(v1); v2 = siluf_(v2); v3 = siluf_(v3); }
        uint2 pk = pack4bf(v0, v1, v2, v3);
        *(uint2*)((is_z ? siluz : xcraw) + obase) = pk;
    }
}

// ---------------------------------------------------------------- K2a: depthwise causal conv(4) + bias + silu
__global__ __launch_bounds__(256) void k2a_conv(const u16* __restrict__ xcraw,
        const float* __restrict__ cw, const float* __restrict__ cb, u16* __restrict__ xcact)
{
    int idx = blockIdx.x * 256 + threadIdx.x;     // NROW*DI/4 total
    int c4   = (idx & 255) * 4;
    int grow = idx >> 8;                          // 0..32767
    int l = grow & 2047;
    int g = grow >> 13;
    size_t rowbase = (size_t)grow * DI + c4;
    float v[4][4];
    #pragma unroll
    for (int t = 0; t < 4; ++t){
        int lt = l - 3 + t;
        if (lt >= 0){
            uint2 p = *(const uint2*)(xcraw + rowbase + (size_t)(t - 3) * DI);
            v[t][0] = bf2f((u16)(p.x & 0xffff)); v[t][1] = bf2f((u16)(p.x >> 16));
            v[t][2] = bf2f((u16)(p.y & 0xffff)); v[t][3] = bf2f((u16)(p.y >> 16));
        } else {
            v[t][0] = v[t][1] = v[t][2] = v[t][3] = 0.0f;
        }
    }
    const float* wc = cw + ((size_t)g * DI + c4) * 4;   // 16 consecutive floats
    float4 w0 = *(const float4*)(wc + 0);
    float4 w1 = *(const float4*)(wc + 4);
    float4 w2 = *(const float4*)(wc + 8);
    float4 w3 = *(const float4*)(wc + 12);
    float4 bias = *(const float4*)(cb + (size_t)g * DI + c4);
    float wj[4][4] = {{w0.x,w0.y,w0.z,w0.w},{w1.x,w1.y,w1.z,w1.w},
                      {w2.x,w2.y,w2.z,w2.w},{w3.x,w3.y,w3.z,w3.w}};
    float bj[4] = {bias.x, bias.y, bias.z, bias.w};
    float o[4];
    #pragma unroll
    for (int j = 0; j < 4; ++j){
        float s = bj[j];
        #pragma unroll
        for (int t = 0; t < 4; ++t) s = fmaf(wj[j][t], v[t][j], s);
        o[j] = siluf_(s);
    }
    *(uint2*)(xcact + rowbase) = pack4bf(o[0], o[1], o[2], o[3]);
}

// ---------------------------------------------------------------- K2b: xp = xc @ xproj_w -> delta(softplus), B, C
__global__ __launch_bounds__(256) void k2b_xproj(const u16* __restrict__ xcact,
        const float* __restrict__ wt, float* __restrict__ delta,
        float* __restrict__ bsel, float* __restrict__ csel)
{
    __shared__ float xcs[8][1024];
    const int row0 = blockIdx.x * 8;
    const int g = row0 >> 13;
    const int tid = threadIdx.x;
    for (int i = tid; i < 2048; i += 256){
        int rr = i >> 8;
        int doff = (i & 255) * 4;
        uint2 p = *(const uint2*)(xcact + (size_t)(row0 + rr) * DI + doff);
        xcs[rr][doff + 0] = bf2f((u16)(p.x & 0xffff));
        xcs[rr][doff + 1] = bf2f((u16)(p.x >> 16));
        xcs[rr][doff + 2] = bf2f((u16)(p.y & 0xffff));
        xcs[rr][doff + 3] = bf2f((u16)(p.y >> 16));
    }
    __syncthreads();
    {
        const int o = tid & 31, rr = tid >> 5;
        const float* wcol = wt + ((size_t)g * 33 + o) * DI;
        float acc = 0.0f;
        for (int d = 0; d < DI; d += 4){
            float4 xv = *(const float4*)&xcs[rr][d];
            float4 wv = *(const float4*)(wcol + d);
            acc = fmaf(xv.x, wv.x, acc); acc = fmaf(xv.y, wv.y, acc);
            acc = fmaf(xv.z, wv.z, acc); acc = fmaf(xv.w, wv.w, acc);
        }
        int grow = row0 + rr;
        if (o == 0)       delta[grow] = softplusf_(acc);
        else if (o < 17)  bsel[(size_t)grow * DS + (o - 1)]  = acc;
        else              csel[(size_t)grow * DS + (o - 17)] = acc;
    }
    if (tid < 8){
        const int rr = tid;
        const float* wcol = wt + ((size_t)g * 33 + 32) * DI;
        float acc = 0.0f;
        for (int d = 0; d < DI; d += 4){
            float4 xv = *(const float4*)&xcs[rr][d];
            float4 wv = *(const float4*)(wcol + d);
            acc = fmaf(xv.x, wv.x, acc); acc = fmaf(xv.y, wv.y, acc);
            acc = fmaf(xv.z, wv.z, acc); acc = fmaf(xv.w, wv.w, acc);
        }
        csel[(size_t)(row0 + rr) * DS + 15] = acc;
    }
}

// ---------------------------------------------------------------- K3: sequential scan + D-term + silu(z) gating -> yg (bf16)
__global__ __launch_bounds__(256) void k3_scan(const u16* __restrict__ xcact,
        const u16* __restrict__ siluz, const float* __restrict__ delta,
        const float* __restrict__ bsel, const float* __restrict__ csel,
        const float* __restrict__ A_log, const float* __restrict__ Dp,
        u16* __restrict__ yg)
{
    __shared__ float sd[64];
    __shared__ float sB[1024], sC[1024], sx[1024], sz[1024], sy[1024];
    const int g = blockIdx.z, b = blockIdx.y;
    const int c0 = blockIdx.x * 16;
    const int tid = threadIdx.x;
    const int s   = tid & 15;
    const int cib = tid >> 4;                 // 0..15 channel-in-block
    const int c   = c0 + cib;
    const float A_ls = -__expf(A_log[((size_t)g * DI + c) * DS + s]);
    const float dpc  = Dp[(size_t)g * DI + c];
    const size_t gbbase = ((size_t)(g * BZ + b)) * LSEQ;
    float h = 0.0f;
    const int lr = tid >> 2;                  // 0..63 staging row
    const int lc = (tid & 3) * 4;             // staging col
    for (int l0 = 0; l0 < LSEQ; l0 += 64){
        size_t rb = gbbase + l0;
        if (tid < 64) sd[tid] = delta[rb + tid];
        *(float4*)&sB[tid * 4] = *(const float4*)&bsel[rb * DS + tid * 4];
        *(float4*)&sC[tid * 4] = *(const float4*)&csel[rb * DS + tid * 4];
        {
            uint2 p = *(const uint2*)(xcact + (rb + lr) * DI + c0 + lc);
            sx[lr * 16 + lc + 0] = bf2f((u16)(p.x & 0xffff));
            sx[lr * 16 + lc + 1] = bf2f((u16)(p.x >> 16));
            sx[lr * 16 + lc + 2] = bf2f((u16)(p.y & 0xffff));
            sx[lr * 16 + lc + 3] = bf2f((u16)(p.y >> 16));
            uint2 q = *(const uint2*)(siluz + (rb + lr) * DI + c0 + lc);
            sz[lr * 16 + lc + 0] = bf2f((u16)(q.x & 0xffff));
            sz[lr * 16 + lc + 1] = bf2f((u16)(q.x >> 16));
            sz[lr * 16 + lc + 2] = bf2f((u16)(q.y & 0xffff));
            sz[lr * 16 + lc + 3] = bf2f((u16)(q.y >> 16));
        }
        __syncthreads();
        #pragma unroll 4
        for (int t = 0; t < 64; ++t){
            float dlt = sd[t];
            float a = __expf(dlt * A_ls);
            float xv = sx[t * 16 + cib];
            h = fmaf(a, h, dlt * sB[t * 16 + s] * xv);
            float p = h * sC[t * 16 + s];
            p += __shfl_xor(p, 1);
            p += __shfl_xor(p, 2);
            p += __shfl_xor(p, 4);
            p += __shfl_xor(p, 8);
            if (s == 0) sy[t * 16 + cib] = (p + xv * dpc) * sz[t * 16 + cib];
        }
        __syncthreads();
        {
            float y0 = sy[lr * 16 + lc + 0], y1 = sy[lr * 16 + lc + 1];
            float y2 = sy[lr * 16 + lc + 2], y3 = sy[lr * 16 + lc + 3];
            *(uint2*)(yg + (rb + lr) * DI + c0 + lc) = pack4bf(y0, y1, y2, y3);
        }
        __syncthreads();
    }
}

// ---------------------------------------------------------------- K4: outs = yg @ out_w[g]  (A bf16, fp32 out)
__global__ __launch_bounds__(256) void k4_gemm_out(const u16* __restrict__ Abf,
        const float* __restrict__ W_all, float* __restrict__ outs)
{
    const int g    = blockIdx.z;
    const int n0   = blockIdx.x * 64;
    const int row0 = blockIdx.y * 64;
    const float* W = W_all + (size_t)g * DI * DM;
    __shared__ float As[16][68];
    __shared__ float Bs[16][68];
    const int tid = threadIdx.x;
    const int tx = tid & 15, ty = tid >> 4;
    float acc[4][4] = {};
    const int a_row = tid >> 2;
    const int a_k   = (tid & 3) * 4;
    const u16* aptr = Abf + ((size_t)g * RB + row0 + a_row) * DI;
    const int b_k = tid >> 4;
    const int b_n = (tid & 15) * 4;
    for (int k0 = 0; k0 < DI; k0 += 16){
        uint2 av = *(const uint2*)(aptr + k0 + a_k);
        float4 bv = *(const float4*)(W + (size_t)(k0 + b_k) * DM + n0 + b_n);
        __syncthreads();
        As[a_k + 0][a_row] = bf2f((u16)(av.x & 0xffff));
        As[a_k + 1][a_row] = bf2f((u16)(av.x >> 16));
        As[a_k + 2][a_row] = bf2f((u16)(av.y & 0xffff));
        As[a_k + 3][a_row] = bf2f((u16)(av.y >> 16));
        *(float4*)&Bs[b_k][b_n] = bv;
        __syncthreads();
        #pragma unroll
        for (int kk = 0; kk < 16; ++kk){
            const float4 a4 = *(const float4*)&As[kk][ty * 4];
            const float4 b4 = *(const float4*)&Bs[kk][tx * 4];
            float ar[4] = {a4.x, a4.y, a4.z, a4.w};
            float br[4] = {b4.x, b4.y, b4.z, b4.w};
            #pragma unroll
            for (int i = 0; i < 4; ++i)
                #pragma unroll
                for (int j = 0; j < 4; ++j)
                    acc[i][j] = fmaf(ar[i], br[j], acc[i][j]);
        }
    }
    #pragma unroll
    for (int i = 0; i < 4; ++i){
        size_t obase = ((size_t)g * RB + row0 + ty * 4 + i) * DM + n0 + tx * 4;
        float4 v; v.x = acc[i][0]; v.y = acc[i][1]; v.z = acc[i][2]; v.w = acc[i][3];
        *(float4*)(outs + obase) = v;
    }
}

// ---------------------------------------------------------------- K5: combine + gate GEMM + residual + LayerNorm
__global__ __launch_bounds__(256) void k5_combine(const float* __restrict__ outs,
        const float* __restrict__ x, const float* __restrict__ gw, const float* __restrict__ gb,
        const float* __restrict__ lnw, const float* __restrict__ lnb, float* __restrict__ out)
{
    __shared__ float sh[8][512];
    __shared__ float sv[8][512];
    __shared__ float syb[8][512];
    const int tid = threadIdx.x;
    const int r0 = blockIdx.x * 8;
    const int b = r0 >> 11;
    for (int i = tid; i < 1024; i += 256){
        int rr = i >> 7, j4 = (i & 127) * 4;
        int l = (r0 + rr) & 2047, lf = 2047 - l;
        float4 o0 = *(const float4*)(outs + ((size_t)(0 * BZ + b) * LSEQ + l ) * DM + j4);
        float4 o1 = *(const float4*)(outs + ((size_t)(1 * BZ + b) * LSEQ + lf) * DM + j4);
        float4 o2 = *(const float4*)(outs + ((size_t)(2 * BZ + b) * LSEQ + l ) * DM + j4);
        float4 o3 = *(const float4*)(outs + ((size_t)(3 * BZ + b) * LSEQ + lf) * DM + j4);
        float4 hh, hv;
        hh.x = 0.5f * (o0.x + o1.x); hh.y = 0.5f * (o0.y + o1.y);
        hh.z = 0.5f * (o0.z + o1.z); hh.w = 0.5f * (o0.w + o1.w);
        hv.x = 0.5f * (o2.x + o3.x); hv.y = 0.5f * (o2.y + o3.y);
        hv.z = 0.5f * (o2.z + o3.z); hv.w = 0.5f * (o2.w + o3.w);
        *(float4*)&sh[rr][j4] = hh;
        *(float4*)&sv[rr][j4] = hv;
    }
    __syncthreads();
    float acc0[8] = {}, acc1[8] = {};
    const int j0 = tid, j1 = tid + 256;
    for (int k = 0; k < 512; ++k){
        float w0 = gw[(size_t)k * DM + j0];
        float w1 = gw[(size_t)k * DM + j1];
        #pragma unroll
        for (int rr = 0; rr < 8; ++rr){
            float hk = sh[rr][k];
            acc0[rr] = fmaf(hk, w0, acc0[rr]);
            acc1[rr] = fmaf(hk, w1, acc1[rr]);
        }
    }
    for (int k = 0; k < 512; ++k){
        float w0 = gw[(size_t)(k + 512) * DM + j0];
        float w1 = gw[(size_t)(k + 512) * DM + j1];
        #pragma unroll
        for (int rr = 0; rr < 8; ++rr){
            float hk = sv[rr][k];
            acc0[rr] = fmaf(hk, w0, acc0[rr]);
            acc1[rr] = fmaf(hk, w1, acc1[rr]);
        }
    }
    const float gb0 = gb[j0], gb1 = gb[j1];
    #pragma unroll
    for (int rr = 0; rr < 8; ++rr){
        int l = (r0 + rr) & 2047;
        size_t xbase = ((size_t)b * LSEQ + l) * DM;
        float g0 = sigmoidf_(acc0[rr] + gb0);
        float g1 = sigmoidf_(acc1[rr] + gb1);
        syb[rr][j0] = g0 * sh[rr][j0] + (1.0f - g0) * sv[rr][j0] + x[xbase + j0];
        syb[rr][j1] = g1 * sh[rr][j1] + (1.0f - g1) * sv[rr][j1] + x[xbase + j1];
    }
    __syncthreads();
    const int wv = tid >> 6, lane = tid & 63;
    for (int half = 0; half < 2; ++half){
        int rr = wv + half * 4;
        float sum = 0.0f, sq = 0.0f;
        #pragma unroll
        for (int i = 0; i < 8; ++i){
            float v = syb[rr][lane + i * 64];
            sum += v; sq = fmaf(v, v, sq);
        }
        #pragma unroll
        for (int m = 1; m < 64; m <<= 1){
            sum += __shfl_xor(sum, m);
            sq  += __shfl_xor(sq, m);
        }
        float mu = sum * (1.0f / 512.0f);
        float var = sq * (1.0f / 512.0f) - mu * mu;
        float rstd = rsqrtf(var + 1e-5f);
        int l = (r0 + rr) & 2047;
        size_t obase = ((size_t)b * LSEQ + l) * DM;
        #pragma unroll
        for (int i = 0; i < 8; ++i){
            int j = lane + i * 64;
            out[obase + j] = (syb[rr][j] - mu) * rstd * lnw[j] + lnb[j];
        }
    }
}

// ----------------------------------------------------------------
extern "C" void kernel_launch(void* const* d_in, const int* in_sizes, int n_in,
                              void* d_out, int out_size, void* d_ws, size_t ws_size,
                              hipStream_t stream)
{
    const float* x      = (const float*)d_in[0];
    const float* in_w   = (const float*)d_in[1];
    const float* conv_w = (const float*)d_in[2];
    const float* conv_b = (const float*)d_in[3];
    const float* xproj_w= (const float*)d_in[4];
    const float* A_log  = (const float*)d_in[5];
    const float* D_par  = (const float*)d_in[6];
    const float* out_w  = (const float*)d_in[7];
    const float* gate_w = (const float*)d_in[8];
    const float* gate_b = (const float*)d_in[9];
    const float* ln_w   = (const float*)d_in[10];
    const float* ln_b   = (const float*)d_in[11];
    float* out = (float*)d_out;

    char* ws = (char*)d_ws;
    // bf16 big buffers: 33,554,432 elems each = 67,108,864 B
    u16* XCRAW = (u16*)(ws + 0);
    u16* SILUZ = (u16*)(ws + 67108864);
    u16* XCACT = (u16*)(ws + 134217728);
    float* DELTA = (float*)(ws + 201326592);   // 32768 f
    float* BSEL  = (float*)(ws + 201457664);   // 524288 f
    float* CSEL  = (float*)(ws + 203554816);   // 524288 f
    float* WT    = (float*)(ws + 205651968);   // 135168 f
    u16*   YG    = XCRAW;                       // alias: xcraw dead after K2a
    float* OUTS  = (float*)(ws + 67108864);     // alias SILUZ: z dead after K3 (exactly 64MB)

    k0_transpose_xproj<<<(G * 33 * DI + 255) / 256, 256, 0, stream>>>(xproj_w, WT);

    dim3 g1(2 * DI / 64, RB / 64, G);
    k1_gemm_in<<<g1, 256, 0, stream>>>(x, in_w, XCRAW, SILUZ);

    k2a_conv<<<(NROW * (DI / 4)) / 256, 256, 0, stream>>>(XCRAW, conv_w, conv_b, XCACT);

    k2b_xproj<<<NROW / 8, 256, 0, stream>>>(XCACT, WT, DELTA, BSEL, CSEL);

    dim3 g3(DI / 16, BZ, G);
    k3_scan<<<g3, 256, 0, stream>>>(XCACT, SILUZ, DELTA, BSEL, CSEL, A_log, D_par, YG);

    dim3 g4(DM / 64, RB / 64, G);
    k4_gemm_out<<<g4, 256, 0, stream>>>(YG, out_w, OUTS);

    k5_combine<<<RB / 8, 256, 0, stream>>>(OUTS, x, gate_w, gate_b, ln_w, ln_b, out);
}

// Round 2
// 1472.115 us; speedup vs baseline: 1.8680x; 1.8680x over previous
//
#include <hip/hip_runtime.h>
#include <hip/hip_bf16.h>
#include <math.h>

#define G 4
#define BZ 4
#define LSEQ 2048
#define DM 512
#define DI 1024
#define DS 16
#define NROW (G*BZ*LSEQ)   /* 32768 */
#define RB (BZ*LSEQ)       /* 8192 rows per ssm-block */

typedef unsigned short u16;
typedef unsigned int u32;

using short8 = __attribute__((ext_vector_type(8))) short;
using f32x4  = __attribute__((ext_vector_type(4))) float;

__device__ __forceinline__ float bf2f(u16 v){ return __uint_as_float(((u32)v) << 16); }
__device__ __forceinline__ u16 f2bf(float f){
    u32 u = __float_as_uint(f);
    u32 r = (u + 0x7FFFu + ((u >> 16) & 1u)) >> 16;   // RNE
    return (u16)r;
}
__device__ __forceinline__ float sigmoidf_(float x){ return 1.0f / (1.0f + __expf(-x)); }
__device__ __forceinline__ float siluf_(float x){ return x / (1.0f + __expf(-x)); }
__device__ __forceinline__ float softplusf_(float v){
    return fmaxf(v, 0.0f) + log1pf(__expf(-fabsf(v)));
}
__device__ __forceinline__ uint2 pack4bf(float a, float b, float c, float d){
    uint2 p;
    p.x = (u32)f2bf(a) | ((u32)f2bf(b) << 16);
    p.y = (u32)f2bf(c) | ((u32)f2bf(d) << 16);
    return p;
}
__device__ __forceinline__ void gl2lds16(const u16* g, u16* l){
    __builtin_amdgcn_global_load_lds(
        (const __attribute__((address_space(1))) u32*)g,
        (__attribute__((address_space(3))) u32*)l, 16, 0, 0);
}

// ---------------------------------------------------------------- P0: x fp32 -> bf16
__global__ void p0_xbf(const float* __restrict__ x, u16* __restrict__ xbf){
    size_t i = (size_t)(blockIdx.x * 256 + threadIdx.x) * 4;
    float4 v = *(const float4*)(x + i);
    *(uint2*)(xbf + i) = pack4bf(v.x, v.y, v.z, v.w);
}

// ---------------------------------------------------------------- PT: [g][R][C] fp32 -> [g][C][R] bf16 (tiled transpose)
__global__ __launch_bounds__(256) void pT(const float* __restrict__ in, u16* __restrict__ out,
                                          int R, int C){
    __shared__ float tl[64][65];
    const int g = blockIdx.z;
    const int r0 = blockIdx.x * 64, c0 = blockIdx.y * 64;
    const int t = threadIdx.x;
    #pragma unroll
    for (int p = 0; p < 4; ++p){
        int r = p * 16 + (t >> 4);
        int c = (t & 15) * 4;
        float4 v = *(const float4*)(in + ((size_t)g * R + r0 + r) * C + c0 + c);
        tl[r][c] = v.x; tl[r][c+1] = v.y; tl[r][c+2] = v.z; tl[r][c+3] = v.w;
    }
    __syncthreads();
    #pragma unroll
    for (int p = 0; p < 4; ++p){
        int oc = p * 16 + (t >> 4);      // output row (= input col)
        int orr = (t & 15) * 4;          // output cols (= input rows), 4 consecutive
        uint2 pk = pack4bf(tl[orr][oc], tl[orr+1][oc], tl[orr+2][oc], tl[orr+3][oc]);
        *(uint2*)(out + ((size_t)g * C + c0 + oc) * R + r0 + orr) = pk;
    }
}

// ---------------------------------------------------------------- K0: xproj_w [g][d][33] -> WT [g][o][d]
__global__ void k0_transpose_xproj(const float* __restrict__ xw, float* __restrict__ wt){
    int i = blockIdx.x * 256 + threadIdx.x;
    if (i >= G * 33 * DI) return;
    int d  = i & (DI - 1);
    int go = i >> 10;          // g*33 + o
    int o  = go % 33;
    int g  = go / 33;
    wt[i] = xw[((size_t)g * DI + d) * 33 + o];
}

// ---------------------------------------------------------------- K1: xz = Xin[g] @ in_w[g] via MFMA; split -> xcraw(bf16), silu(z)(bf16)
// A = XBF [8192][512] (row-gathered, flipped for odd g), B^T = INWT [g][2048][512]
__global__ __launch_bounds__(256) void k1_mfma(const u16* __restrict__ XBF,
        const u16* __restrict__ INWT, u16* __restrict__ xcraw, u16* __restrict__ siluz)
{
    __shared__ __align__(16) u16 As[128 * 32];
    __shared__ __align__(16) u16 Bs[128 * 32];
    const int g    = blockIdx.z;
    const int n0   = blockIdx.x * 128;
    const int row0 = blockIdx.y * 128;
    const int tid  = threadIdx.x;
    const int w = tid >> 6, lane = tid & 63;
    const int wr = w >> 1, wc = w & 1;
    // staging source pointers (2 issues of 64 rows each, 4 lanes/row x 16B)
    const int srow = tid >> 2;     // 0..63
    const int kgrp = tid & 3;
    const u16* pA[2]; const u16* pB[2];
    #pragma unroll
    for (int i = 0; i < 2; ++i){
        int r = row0 + i * 64 + srow;
        int b = r >> 11, l = r & 2047;
        int lsrc = (g & 1) ? (2047 - l) : l;
        pA[i] = XBF  + ((size_t)((b << 11) + lsrc)) * DM + kgrp * 8;
        pB[i] = INWT + ((size_t)(g * 2048 + n0 + i * 64 + srow)) * DM + kgrp * 8;
    }
    u16* ldsA = As + w * 512;      // wave base (1024B per wave)
    u16* ldsB = Bs + w * 512;
    f32x4 acc[4][4];
    #pragma unroll
    for (int mi = 0; mi < 4; ++mi)
        #pragma unroll
        for (int ni = 0; ni < 4; ++ni)
            acc[mi][ni] = (f32x4){0.f, 0.f, 0.f, 0.f};
    const int ro = lane & 15;
    const int ko = (lane >> 4) * 8;
    for (int k0 = 0; k0 < DM; k0 += 32){
        gl2lds16(pA[0] + k0, ldsA);
        gl2lds16(pA[1] + k0, ldsA + 2048);
        gl2lds16(pB[0] + k0, ldsB);
        gl2lds16(pB[1] + k0, ldsB + 2048);
        __syncthreads();           // drains vmcnt+lgkm in all waves, then barrier
        short8 af[4], bfr[4];
        #pragma unroll
        for (int mi = 0; mi < 4; ++mi)
            af[mi] = *(const short8*)&As[(wr * 64 + mi * 16 + ro) * 32 + ko];
        #pragma unroll
        for (int ni = 0; ni < 4; ++ni)
            bfr[ni] = *(const short8*)&Bs[(wc * 64 + ni * 16 + ro) * 32 + ko];
        #pragma unroll
        for (int mi = 0; mi < 4; ++mi)
            #pragma unroll
            for (int ni = 0; ni < 4; ++ni)
                acc[mi][ni] = __builtin_amdgcn_mfma_f32_16x16x32_bf16(af[mi], bfr[ni], acc[mi][ni], 0, 0, 0);
        __syncthreads();           // frag reads done before next stage overwrites
    }
    const bool is_z = (n0 >= DI);
    u16* outp = is_z ? siluz : xcraw;
    const int colb = n0 - (is_z ? DI : 0) + wc * 64 + (lane & 15);
    #pragma unroll
    for (int mi = 0; mi < 4; ++mi){
        #pragma unroll
        for (int rr = 0; rr < 4; ++rr){
            int r = row0 + wr * 64 + mi * 16 + (lane >> 4) * 4 + rr;
            int b = r >> 11, l = r & 2047;
            size_t rowbase = ((size_t)(g * BZ + b) * LSEQ + l) * DI;
            #pragma unroll
            for (int ni = 0; ni < 4; ++ni){
                float v = acc[mi][ni][rr];
                if (is_z) v = siluf_(v);
                outp[rowbase + colb + ni * 16] = f2bf(v);
            }
        }
    }
}

// ---------------------------------------------------------------- K2a: depthwise causal conv(4) + bias + silu
__global__ __launch_bounds__(256) void k2a_conv(const u16* __restrict__ xcraw,
        const float* __restrict__ cw, const float* __restrict__ cb, u16* __restrict__ xcact)
{
    int idx = blockIdx.x * 256 + threadIdx.x;     // NROW*DI/4 total
    int c4   = (idx & 255) * 4;
    int grow = idx >> 8;                          // 0..32767
    int l = grow & 2047;
    int g = grow >> 13;
    size_t rowbase = (size_t)grow * DI + c4;
    float v[4][4];
    #pragma unroll
    for (int t = 0; t < 4; ++t){
        int lt = l - 3 + t;
        if (lt >= 0){
            uint2 p = *(const uint2*)(xcraw + rowbase + (size_t)(t - 3) * DI);
            v[t][0] = bf2f((u16)(p.x & 0xffff)); v[t][1] = bf2f((u16)(p.x >> 16));
            v[t][2] = bf2f((u16)(p.y & 0xffff)); v[t][3] = bf2f((u16)(p.y >> 16));
        } else {
            v[t][0] = v[t][1] = v[t][2] = v[t][3] = 0.0f;
        }
    }
    const float* wc = cw + ((size_t)g * DI + c4) * 4;   // 16 consecutive floats
    float4 w0 = *(const float4*)(wc + 0);
    float4 w1 = *(const float4*)(wc + 4);
    float4 w2 = *(const float4*)(wc + 8);
    float4 w3 = *(const float4*)(wc + 12);
    float4 bias = *(const float4*)(cb + (size_t)g * DI + c4);
    float wj[4][4] = {{w0.x,w0.y,w0.z,w0.w},{w1.x,w1.y,w1.z,w1.w},
                      {w2.x,w2.y,w2.z,w2.w},{w3.x,w3.y,w3.z,w3.w}};
    float bj[4] = {bias.x, bias.y, bias.z, bias.w};
    float o[4];
    #pragma unroll
    for (int j = 0; j < 4; ++j){
        float s = bj[j];
        #pragma unroll
        for (int t = 0; t < 4; ++t) s = fmaf(wj[j][t], v[t][j], s);
        o[j] = siluf_(s);
    }
    *(uint2*)(xcact + rowbase) = pack4bf(o[0], o[1], o[2], o[3]);
}

// ---------------------------------------------------------------- K2b: xp = xc @ xproj_w -> delta(softplus), B, C
__global__ __launch_bounds__(256) void k2b_xproj(const u16* __restrict__ xcact,
        const float* __restrict__ wt, float* __restrict__ delta,
        float* __restrict__ bsel, float* __restrict__ csel)
{
    __shared__ float xcs[8][1024];
    const int row0 = blockIdx.x * 8;
    const int g = row0 >> 13;
    const int tid = threadIdx.x;
    for (int i = tid; i < 2048; i += 256){
        int rr = i >> 8;
        int doff = (i & 255) * 4;
        uint2 p = *(const uint2*)(xcact + (size_t)(row0 + rr) * DI + doff);
        xcs[rr][doff + 0] = bf2f((u16)(p.x & 0xffff));
        xcs[rr][doff + 1] = bf2f((u16)(p.x >> 16));
        xcs[rr][doff + 2] = bf2f((u16)(p.y & 0xffff));
        xcs[rr][doff + 3] = bf2f((u16)(p.y >> 16));
    }
    __syncthreads();
    {
        const int o = tid & 31, rr = tid >> 5;
        const float* wcol = wt + ((size_t)g * 33 + o) * DI;
        float acc = 0.0f;
        for (int d = 0; d < DI; d += 4){
            float4 xv = *(const float4*)&xcs[rr][d];
            float4 wv = *(const float4*)(wcol + d);
            acc = fmaf(xv.x, wv.x, acc); acc = fmaf(xv.y, wv.y, acc);
            acc = fmaf(xv.z, wv.z, acc); acc = fmaf(xv.w, wv.w, acc);
        }
        int grow = row0 + rr;
        if (o == 0)       delta[grow] = softplusf_(acc);
        else if (o < 17)  bsel[(size_t)grow * DS + (o - 1)]  = acc;
        else              csel[(size_t)grow * DS + (o - 17)] = acc;
    }
    if (tid < 8){
        const int rr = tid;
        const float* wcol = wt + ((size_t)g * 33 + 32) * DI;
        float acc = 0.0f;
        for (int d = 0; d < DI; d += 4){
            float4 xv = *(const float4*)&xcs[rr][d];
            float4 wv = *(const float4*)(wcol + d);
            acc = fmaf(xv.x, wv.x, acc); acc = fmaf(xv.y, wv.y, acc);
            acc = fmaf(xv.z, wv.z, acc); acc = fmaf(xv.w, wv.w, acc);
        }
        csel[(size_t)(row0 + rr) * DS + 15] = acc;
    }
}

// ---------------------------------------------------------------- K3: sequential scan + D-term + silu(z) gating -> yg (bf16)
__global__ __launch_bounds__(256) void k3_scan(const u16* __restrict__ xcact,
        const u16* __restrict__ siluz, const float* __restrict__ delta,
        const float* __restrict__ bsel, const float* __restrict__ csel,
        const float* __restrict__ A_log, const float* __restrict__ Dp,
        u16* __restrict__ yg)
{
    __shared__ float sd[64];
    __shared__ float sB[1024], sC[1024], sx[1024], sz[1024], sy[1024];
    const int g = blockIdx.z, b = blockIdx.y;
    const int c0 = blockIdx.x * 16;
    const int tid = threadIdx.x;
    const int s   = tid & 15;
    const int cib = tid >> 4;                 // 0..15 channel-in-block
    const int c   = c0 + cib;
    const float A_ls = -__expf(A_log[((size_t)g * DI + c) * DS + s]);
    const float dpc  = Dp[(size_t)g * DI + c];
    const size_t gbbase = ((size_t)(g * BZ + b)) * LSEQ;
    float h = 0.0f;
    const int lr = tid >> 2;                  // 0..63 staging row
    const int lc = (tid & 3) * 4;             // staging col
    for (int l0 = 0; l0 < LSEQ; l0 += 64){
        size_t rb = gbbase + l0;
        if (tid < 64) sd[tid] = delta[rb + tid];
        *(float4*)&sB[tid * 4] = *(const float4*)&bsel[rb * DS + tid * 4];
        *(float4*)&sC[tid * 4] = *(const float4*)&csel[rb * DS + tid * 4];
        {
            uint2 p = *(const uint2*)(xcact + (rb + lr) * DI + c0 + lc);
            sx[lr * 16 + lc + 0] = bf2f((u16)(p.x & 0xffff));
            sx[lr * 16 + lc + 1] = bf2f((u16)(p.x >> 16));
            sx[lr * 16 + lc + 2] = bf2f((u16)(p.y & 0xffff));
            sx[lr * 16 + lc + 3] = bf2f((u16)(p.y >> 16));
            uint2 q = *(const uint2*)(siluz + (rb + lr) * DI + c0 + lc);
            sz[lr * 16 + lc + 0] = bf2f((u16)(q.x & 0xffff));
            sz[lr * 16 + lc + 1] = bf2f((u16)(q.x >> 16));
            sz[lr * 16 + lc + 2] = bf2f((u16)(q.y & 0xffff));
            sz[lr * 16 + lc + 3] = bf2f((u16)(q.y >> 16));
        }
        __syncthreads();
        #pragma unroll 4
        for (int t = 0; t < 64; ++t){
            float dlt = sd[t];
            float a = __expf(dlt * A_ls);
            float xv = sx[t * 16 + cib];
            h = fmaf(a, h, dlt * sB[t * 16 + s] * xv);
            float p = h * sC[t * 16 + s];
            p += __shfl_xor(p, 1);
            p += __shfl_xor(p, 2);
            p += __shfl_xor(p, 4);
            p += __shfl_xor(p, 8);
            if (s == 0) sy[t * 16 + cib] = (p + xv * dpc) * sz[t * 16 + cib];
        }
        __syncthreads();
        {
            float y0 = sy[lr * 16 + lc + 0], y1 = sy[lr * 16 + lc + 1];
            float y2 = sy[lr * 16 + lc + 2], y3 = sy[lr * 16 + lc + 3];
            *(uint2*)(yg + (rb + lr) * DI + c0 + lc) = pack4bf(y0, y1, y2, y3);
        }
        __syncthreads();
    }
}

// ---------------------------------------------------------------- K4: outs = yg @ out_w[g] via MFMA (fp32 out)
// A = YG [g][8192][1024] bf16, B^T = OUTWT [g][512][1024] bf16
__global__ __launch_bounds__(256) void k4_mfma(const u16* __restrict__ YG,
        const u16* __restrict__ OUTWT, float* __restrict__ outs)
{
    __shared__ __align__(16) u16 As[128 * 32];
    __shared__ __align__(16) u16 Bs[128 * 32];
    const int g    = blockIdx.z;
    const int n0   = blockIdx.x * 128;
    const int row0 = blockIdx.y * 128;
    const int tid  = threadIdx.x;
    const int w = tid >> 6, lane = tid & 63;
    const int wr = w >> 1, wc = w & 1;
    const int srow = tid >> 2;
    const int kgrp = tid & 3;
    const u16* pA[2]; const u16* pB[2];
    #pragma unroll
    for (int i = 0; i < 2; ++i){
        pA[i] = YG    + ((size_t)(g * RB  + row0 + i * 64 + srow)) * DI + kgrp * 8;
        pB[i] = OUTWT + ((size_t)(g * DM  + n0   + i * 64 + srow)) * DI + kgrp * 8;
    }
    u16* ldsA = As + w * 512;
    u16* ldsB = Bs + w * 512;
    f32x4 acc[4][4];
    #pragma unroll
    for (int mi = 0; mi < 4; ++mi)
        #pragma unroll
        for (int ni = 0; ni < 4; ++ni)
            acc[mi][ni] = (f32x4){0.f, 0.f, 0.f, 0.f};
    const int ro = lane & 15;
    const int ko = (lane >> 4) * 8;
    for (int k0 = 0; k0 < DI; k0 += 32){
        gl2lds16(pA[0] + k0, ldsA);
        gl2lds16(pA[1] + k0, ldsA + 2048);
        gl2lds16(pB[0] + k0, ldsB);
        gl2lds16(pB[1] + k0, ldsB + 2048);
        __syncthreads();
        short8 af[4], bfr[4];
        #pragma unroll
        for (int mi = 0; mi < 4; ++mi)
            af[mi] = *(const short8*)&As[(wr * 64 + mi * 16 + ro) * 32 + ko];
        #pragma unroll
        for (int ni = 0; ni < 4; ++ni)
            bfr[ni] = *(const short8*)&Bs[(wc * 64 + ni * 16 + ro) * 32 + ko];
        #pragma unroll
        for (int mi = 0; mi < 4; ++mi)
            #pragma unroll
            for (int ni = 0; ni < 4; ++ni)
                acc[mi][ni] = __builtin_amdgcn_mfma_f32_16x16x32_bf16(af[mi], bfr[ni], acc[mi][ni], 0, 0, 0);
        __syncthreads();
    }
    const int colb = n0 + wc * 64 + (lane & 15);
    #pragma unroll
    for (int mi = 0; mi < 4; ++mi){
        #pragma unroll
        for (int rr = 0; rr < 4; ++rr){
            int r = row0 + wr * 64 + mi * 16 + (lane >> 4) * 4 + rr;
            size_t rowbase = ((size_t)g * RB + r) * DM;
            #pragma unroll
            for (int ni = 0; ni < 4; ++ni)
                outs[rowbase + colb + ni * 16] = acc[mi][ni][rr];
        }
    }
}

// ---------------------------------------------------------------- K5: combine + gate GEMM + residual + LayerNorm
__global__ __launch_bounds__(256) void k5_combine(const float* __restrict__ outs,
        const float* __restrict__ x, const float* __restrict__ gw, const float* __restrict__ gb,
        const float* __restrict__ lnw, const float* __restrict__ lnb, float* __restrict__ out)
{
    __shared__ float sh[8][512];
    __shared__ float sv[8][512];
    __shared__ float syb[8][512];
    const int tid = threadIdx.x;
    const int r0 = blockIdx.x * 8;
    const int b = r0 >> 11;
    for (int i = tid; i < 1024; i += 256){
        int rr = i >> 7, j4 = (i & 127) * 4;
        int l = (r0 + rr) & 2047, lf = 2047 - l;
        float4 o0 = *(const float4*)(outs + ((size_t)(0 * BZ + b) * LSEQ + l ) * DM + j4);
        float4 o1 = *(const float4*)(outs + ((size_t)(1 * BZ + b) * LSEQ + lf) * DM + j4);
        float4 o2 = *(const float4*)(outs + ((size_t)(2 * BZ + b) * LSEQ + l ) * DM + j4);
        float4 o3 = *(const float4*)(outs + ((size_t)(3 * BZ + b) * LSEQ + lf) * DM + j4);
        float4 hh, hv;
        hh.x = 0.5f * (o0.x + o1.x); hh.y = 0.5f * (o0.y + o1.y);
        hh.z = 0.5f * (o0.z + o1.z); hh.w = 0.5f * (o0.w + o1.w);
        hv.x = 0.5f * (o2.x + o3.x); hv.y = 0.5f * (o2.y + o3.y);
        hv.z = 0.5f * (o2.z + o3.z); hv.w = 0.5f * (o2.w + o3.w);
        *(float4*)&sh[rr][j4] = hh;
        *(float4*)&sv[rr][j4] = hv;
    }
    __syncthreads();
    float acc0[8] = {}, acc1[8] = {};
    const int j0 = tid, j1 = tid + 256;
    for (int k = 0; k < 512; ++k){
        float w0 = gw[(size_t)k * DM + j0];
        float w1 = gw[(size_t)k * DM + j1];
        #pragma unroll
        for (int rr = 0; rr < 8; ++rr){
            float hk = sh[rr][k];
            acc0[rr] = fmaf(hk, w0, acc0[rr]);
            acc1[rr] = fmaf(hk, w1, acc1[rr]);
        }
    }
    for (int k = 0; k < 512; ++k){
        float w0 = gw[(size_t)(k + 512) * DM + j0];
        float w1 = gw[(size_t)(k + 512) * DM + j1];
        #pragma unroll
        for (int rr = 0; rr < 8; ++rr){
            float hk = sv[rr][k];
            acc0[rr] = fmaf(hk, w0, acc0[rr]);
            acc1[rr] = fmaf(hk, w1, acc1[rr]);
        }
    }
    const float gb0 = gb[j0], gb1 = gb[j1];
    #pragma unroll
    for (int rr = 0; rr < 8; ++rr){
        int l = (r0 + rr) & 2047;
        size_t xbase = ((size_t)b * LSEQ + l) * DM;
        float g0 = sigmoidf_(acc0[rr] + gb0);
        float g1 = sigmoidf_(acc1[rr] + gb1);
        syb[rr][j0] = g0 * sh[rr][j0] + (1.0f - g0) * sv[rr][j0] + x[xbase + j0];
        syb[rr][j1] = g1 * sh[rr][j1] + (1.0f - g1) * sv[rr][j1] + x[xbase + j1];
    }
    __syncthreads();
    const int wv = tid >> 6, lane = tid & 63;
    for (int half = 0; half < 2; ++half){
        int rr = wv + half * 4;
        float sum = 0.0f, sq = 0.0f;
        #pragma unroll
        for (int i = 0; i < 8; ++i){
            float v = syb[rr][lane + i * 64];
            sum += v; sq = fmaf(v, v, sq);
        }
        #pragma unroll
        for (int m = 1; m < 64; m <<= 1){
            sum += __shfl_xor(sum, m);
            sq  += __shfl_xor(sq, m);
        }
        float mu = sum * (1.0f / 512.0f);
        float var = sq * (1.0f / 512.0f) - mu * mu;
        float rstd = rsqrtf(var + 1e-5f);
        int l = (r0 + rr) & 2047;
        size_t obase = ((size_t)b * LSEQ + l) * DM;
        #pragma unroll
        for (int i = 0; i < 8; ++i){
            int j = lane + i * 64;
            out[obase + j] = (syb[rr][j] - mu) * rstd * lnw[j] + lnb[j];
        }
    }
}

// ----------------------------------------------------------------
extern "C" void kernel_launch(void* const* d_in, const int* in_sizes, int n_in,
                              void* d_out, int out_size, void* d_ws, size_t ws_size,
                              hipStream_t stream)
{
    const float* x      = (const float*)d_in[0];
    const float* in_w   = (const float*)d_in[1];
    const float* conv_w = (const float*)d_in[2];
    const float* conv_b = (const float*)d_in[3];
    const float* xproj_w= (const float*)d_in[4];
    const float* A_log  = (const float*)d_in[5];
    const float* D_par  = (const float*)d_in[6];
    const float* out_w  = (const float*)d_in[7];
    const float* gate_w = (const float*)d_in[8];
    const float* gate_b = (const float*)d_in[9];
    const float* ln_w   = (const float*)d_in[10];
    const float* ln_b   = (const float*)d_in[11];
    float* out = (float*)d_out;

    char* ws = (char*)d_ws;
    // bf16 big buffers: 33,554,432 elems each = 67,108,864 B
    u16* XCRAW = (u16*)(ws + 0);
    u16* SILUZ = (u16*)(ws + 67108864);
    u16* XCACT = (u16*)(ws + 134217728);
    float* DELTA = (float*)(ws + 201326592);   // 32768 f
    float* BSEL  = (float*)(ws + 201457664);   // 524288 f
    float* CSEL  = (float*)(ws + 203554816);   // 524288 f
    float* WT    = (float*)(ws + 205651968);   // 135168 f -> end 206192640
    u16*   INWT  = (u16*)(ws + 206192640);     // 8,388,608 B; OUTWT aliases (written after k1)
    u16*   OUTWT = INWT;
    u16*   XBF   = XCACT;                       // alias: XCACT written only at k2a (after k1)
    u16*   YG    = XCRAW;                       // alias: xcraw dead after K2a
    float* OUTS  = (float*)(ws + 67108864);     // alias SILUZ: z dead after K3 (exactly 64MB)

    p0_xbf<<<4096, 256, 0, stream>>>(x, XBF);
    pT<<<dim3(8, 32, G), 256, 0, stream>>>(in_w, INWT, DM, 2 * DI);     // [512][2048] -> [2048][512]
    k0_transpose_xproj<<<(G * 33 * DI + 255) / 256, 256, 0, stream>>>(xproj_w, WT);

    k1_mfma<<<dim3(16, 64, G), 256, 0, stream>>>(XBF, INWT, XCRAW, SILUZ);

    // out_w transpose AFTER k1 (OUTWT aliases INWT)
    pT<<<dim3(16, 8, G), 256, 0, stream>>>(out_w, OUTWT, DI, DM);       // [1024][512] -> [512][1024]

    k2a_conv<<<(NROW * (DI / 4)) / 256, 256, 0, stream>>>(XCRAW, conv_w, conv_b, XCACT);

    k2b_xproj<<<NROW / 8, 256, 0, stream>>>(XCACT, WT, DELTA, BSEL, CSEL);

    dim3 g3(DI / 16, BZ, G);
    k3_scan<<<g3, 256, 0, stream>>>(XCACT, SILUZ, DELTA, BSEL, CSEL, A_log, D_par, YG);

    k4_mfma<<<dim3(4, 64, G), 256, 0, stream>>>(YG, OUTWT, OUTS);

    k5_combine<<<RB / 8, 256, 0, stream>>>(OUTS, x, gate_w, gate_b, ln_w, ln_b, out);
}

// Round 3
// 1131.854 us; speedup vs baseline: 2.4295x; 1.3006x over previous
//
#include <hip/hip_runtime.h>
#include <hip/hip_bf16.h>
#include <math.h>

#define G 4
#define BZ 4
#define LSEQ 2048
#define DM 512
#define DI 1024
#define DS 16
#define NROW (G*BZ*LSEQ)   /* 32768 */
#define RB (BZ*LSEQ)       /* 8192 rows per ssm-block */
#define PCH 16             /* scan chunks per sequence */
#define CL  (LSEQ/PCH)     /* 128 timesteps per chunk */

typedef unsigned short u16;
typedef unsigned int u32;

using short8 = __attribute__((ext_vector_type(8))) short;
using f32x4  = __attribute__((ext_vector_type(4))) float;

__device__ __forceinline__ float bf2f(u16 v){ return __uint_as_float(((u32)v) << 16); }
__device__ __forceinline__ u16 f2bf(float f){
    u32 u = __float_as_uint(f);
    u32 r = (u + 0x7FFFu + ((u >> 16) & 1u)) >> 16;   // RNE
    return (u16)r;
}
__device__ __forceinline__ float sigmoidf_(float x){ return 1.0f / (1.0f + __expf(-x)); }
__device__ __forceinline__ float siluf_(float x){ return x / (1.0f + __expf(-x)); }
__device__ __forceinline__ float softplusf_(float v){
    return fmaxf(v, 0.0f) + log1pf(__expf(-fabsf(v)));
}
__device__ __forceinline__ uint2 pack4bf(float a, float b, float c, float d){
    uint2 p;
    p.x = (u32)f2bf(a) | ((u32)f2bf(b) << 16);
    p.y = (u32)f2bf(c) | ((u32)f2bf(d) << 16);
    return p;
}
__device__ __forceinline__ void gl2lds16(const u16* g, u16* l){
    __builtin_amdgcn_global_load_lds(
        (const __attribute__((address_space(1))) u32*)g,
        (__attribute__((address_space(3))) u32*)l, 16, 0, 0);
}

// ---------------------------------------------------------------- P0: x fp32 -> bf16
__global__ void p0_xbf(const float* __restrict__ x, u16* __restrict__ xbf){
    size_t i = (size_t)(blockIdx.x * 256 + threadIdx.x) * 4;
    float4 v = *(const float4*)(x + i);
    *(uint2*)(xbf + i) = pack4bf(v.x, v.y, v.z, v.w);
}

// ---------------------------------------------------------------- PT: [g][R][C] fp32 -> [g][C][R] bf16 (tiled transpose)
__global__ __launch_bounds__(256) void pT(const float* __restrict__ in, u16* __restrict__ out,
                                          int R, int C){
    __shared__ float tl[64][65];
    const int g = blockIdx.z;
    const int r0 = blockIdx.x * 64, c0 = blockIdx.y * 64;
    const int t = threadIdx.x;
    #pragma unroll
    for (int p = 0; p < 4; ++p){
        int r = p * 16 + (t >> 4);
        int c = (t & 15) * 4;
        float4 v = *(const float4*)(in + ((size_t)g * R + r0 + r) * C + c0 + c);
        tl[r][c] = v.x; tl[r][c+1] = v.y; tl[r][c+2] = v.z; tl[r][c+3] = v.w;
    }
    __syncthreads();
    #pragma unroll
    for (int p = 0; p < 4; ++p){
        int oc = p * 16 + (t >> 4);      // output row (= input col)
        int orr = (t & 15) * 4;          // output cols (= input rows), 4 consecutive
        uint2 pk = pack4bf(tl[orr][oc], tl[orr+1][oc], tl[orr+2][oc], tl[orr+3][oc]);
        *(uint2*)(out + ((size_t)g * C + c0 + oc) * R + r0 + orr) = pk;
    }
}

// ---------------------------------------------------------------- K0: xproj_w [g][d][33] -> WT [g][o][d]
__global__ void k0_transpose_xproj(const float* __restrict__ xw, float* __restrict__ wt){
    int i = blockIdx.x * 256 + threadIdx.x;
    if (i >= G * 33 * DI) return;
    int d  = i & (DI - 1);
    int go = i >> 10;          // g*33 + o
    int o  = go % 33;
    int g  = go / 33;
    wt[i] = xw[((size_t)g * DI + d) * 33 + o];
}

// ---------------------------------------------------------------- K1: xz = Xin[g] @ in_w[g] via MFMA; split -> xcraw(bf16), silu(z)(bf16)
__global__ __launch_bounds__(256) void k1_mfma(const u16* __restrict__ XBF,
        const u16* __restrict__ INWT, u16* __restrict__ xcraw, u16* __restrict__ siluz)
{
    __shared__ __align__(16) u16 As[128 * 32];
    __shared__ __align__(16) u16 Bs[128 * 32];
    const int g    = blockIdx.z;
    const int n0   = blockIdx.x * 128;
    const int row0 = blockIdx.y * 128;
    const int tid  = threadIdx.x;
    const int w = tid >> 6, lane = tid & 63;
    const int wr = w >> 1, wc = w & 1;
    const int srow = tid >> 2;     // 0..63
    const int kgrp = tid & 3;
    const u16* pA[2]; const u16* pB[2];
    #pragma unroll
    for (int i = 0; i < 2; ++i){
        int r = row0 + i * 64 + srow;
        int b = r >> 11, l = r & 2047;
        int lsrc = (g & 1) ? (2047 - l) : l;
        pA[i] = XBF  + ((size_t)((b << 11) + lsrc)) * DM + kgrp * 8;
        pB[i] = INWT + ((size_t)(g * 2048 + n0 + i * 64 + srow)) * DM + kgrp * 8;
    }
    u16* ldsA = As + w * 512;
    u16* ldsB = Bs + w * 512;
    f32x4 acc[4][4];
    #pragma unroll
    for (int mi = 0; mi < 4; ++mi)
        #pragma unroll
        for (int ni = 0; ni < 4; ++ni)
            acc[mi][ni] = (f32x4){0.f, 0.f, 0.f, 0.f};
    const int ro = lane & 15;
    const int ko = (lane >> 4) * 8;
    for (int k0 = 0; k0 < DM; k0 += 32){
        gl2lds16(pA[0] + k0, ldsA);
        gl2lds16(pA[1] + k0, ldsA + 2048);
        gl2lds16(pB[0] + k0, ldsB);
        gl2lds16(pB[1] + k0, ldsB + 2048);
        __syncthreads();
        short8 af[4], bfr[4];
        #pragma unroll
        for (int mi = 0; mi < 4; ++mi)
            af[mi] = *(const short8*)&As[(wr * 64 + mi * 16 + ro) * 32 + ko];
        #pragma unroll
        for (int ni = 0; ni < 4; ++ni)
            bfr[ni] = *(const short8*)&Bs[(wc * 64 + ni * 16 + ro) * 32 + ko];
        #pragma unroll
        for (int mi = 0; mi < 4; ++mi)
            #pragma unroll
            for (int ni = 0; ni < 4; ++ni)
                acc[mi][ni] = __builtin_amdgcn_mfma_f32_16x16x32_bf16(af[mi], bfr[ni], acc[mi][ni], 0, 0, 0);
        __syncthreads();
    }
    const bool is_z = (n0 >= DI);
    u16* outp = is_z ? siluz : xcraw;
    const int colb = n0 - (is_z ? DI : 0) + wc * 64 + (lane & 15);
    #pragma unroll
    for (int mi = 0; mi < 4; ++mi){
        #pragma unroll
        for (int rr = 0; rr < 4; ++rr){
            int r = row0 + wr * 64 + mi * 16 + (lane >> 4) * 4 + rr;
            int b = r >> 11, l = r & 2047;
            size_t rowbase = ((size_t)(g * BZ + b) * LSEQ + l) * DI;
            #pragma unroll
            for (int ni = 0; ni < 4; ++ni){
                float v = acc[mi][ni][rr];
                if (is_z) v = siluf_(v);
                outp[rowbase + colb + ni * 16] = f2bf(v);
            }
        }
    }
}

// ---------------------------------------------------------------- K2a: depthwise causal conv(4) + bias + silu
__global__ __launch_bounds__(256) void k2a_conv(const u16* __restrict__ xcraw,
        const float* __restrict__ cw, const float* __restrict__ cb, u16* __restrict__ xcact)
{
    int idx = blockIdx.x * 256 + threadIdx.x;
    int c4   = (idx & 255) * 4;
    int grow = idx >> 8;
    int l = grow & 2047;
    int g = grow >> 13;
    size_t rowbase = (size_t)grow * DI + c4;
    float v[4][4];
    #pragma unroll
    for (int t = 0; t < 4; ++t){
        int lt = l - 3 + t;
        if (lt >= 0){
            uint2 p = *(const uint2*)(xcraw + rowbase + (size_t)(t - 3) * DI);
            v[t][0] = bf2f((u16)(p.x & 0xffff)); v[t][1] = bf2f((u16)(p.x >> 16));
            v[t][2] = bf2f((u16)(p.y & 0xffff)); v[t][3] = bf2f((u16)(p.y >> 16));
        } else {
            v[t][0] = v[t][1] = v[t][2] = v[t][3] = 0.0f;
        }
    }
    const float* wc = cw + ((size_t)g * DI + c4) * 4;
    float4 w0 = *(const float4*)(wc + 0);
    float4 w1 = *(const float4*)(wc + 4);
    float4 w2 = *(const float4*)(wc + 8);
    float4 w3 = *(const float4*)(wc + 12);
    float4 bias = *(const float4*)(cb + (size_t)g * DI + c4);
    float wj[4][4] = {{w0.x,w0.y,w0.z,w0.w},{w1.x,w1.y,w1.z,w1.w},
                      {w2.x,w2.y,w2.z,w2.w},{w3.x,w3.y,w3.z,w3.w}};
    float bj[4] = {bias.x, bias.y, bias.z, bias.w};
    float o[4];
    #pragma unroll
    for (int j = 0; j < 4; ++j){
        float s = bj[j];
        #pragma unroll
        for (int t = 0; t < 4; ++t) s = fmaf(wj[j][t], v[t][j], s);
        o[j] = siluf_(s);
    }
    *(uint2*)(xcact + rowbase) = pack4bf(o[0], o[1], o[2], o[3]);
}

// ---------------------------------------------------------------- K2b: xp = xc @ xproj_w -> delta(softplus), B, C
__global__ __launch_bounds__(256) void k2b_xproj(const u16* __restrict__ xcact,
        const float* __restrict__ wt, float* __restrict__ delta,
        float* __restrict__ bsel, float* __restrict__ csel)
{
    __shared__ float xcs[8][1024];
    const int row0 = blockIdx.x * 8;
    const int g = row0 >> 13;
    const int tid = threadIdx.x;
    for (int i = tid; i < 2048; i += 256){
        int rr = i >> 8;
        int doff = (i & 255) * 4;
        uint2 p = *(const uint2*)(xcact + (size_t)(row0 + rr) * DI + doff);
        xcs[rr][doff + 0] = bf2f((u16)(p.x & 0xffff));
        xcs[rr][doff + 1] = bf2f((u16)(p.x >> 16));
        xcs[rr][doff + 2] = bf2f((u16)(p.y & 0xffff));
        xcs[rr][doff + 3] = bf2f((u16)(p.y >> 16));
    }
    __syncthreads();
    {
        const int o = tid & 31, rr = tid >> 5;
        const float* wcol = wt + ((size_t)g * 33 + o) * DI;
        float acc = 0.0f;
        for (int d = 0; d < DI; d += 4){
            float4 xv = *(const float4*)&xcs[rr][d];
            float4 wv = *(const float4*)(wcol + d);
            acc = fmaf(xv.x, wv.x, acc); acc = fmaf(xv.y, wv.y, acc);
            acc = fmaf(xv.z, wv.z, acc); acc = fmaf(xv.w, wv.w, acc);
        }
        int grow = row0 + rr;
        if (o == 0)       delta[grow] = softplusf_(acc);
        else if (o < 17)  bsel[(size_t)grow * DS + (o - 1)]  = acc;
        else              csel[(size_t)grow * DS + (o - 17)] = acc;
    }
    if (tid < 8){
        const int rr = tid;
        const float* wcol = wt + ((size_t)g * 33 + 32) * DI;
        float acc = 0.0f;
        for (int d = 0; d < DI; d += 4){
            float4 xv = *(const float4*)&xcs[rr][d];
            float4 wv = *(const float4*)(wcol + d);
            acc = fmaf(xv.x, wv.x, acc); acc = fmaf(xv.y, wv.y, acc);
            acc = fmaf(xv.z, wv.z, acc); acc = fmaf(xv.w, wv.w, acc);
        }
        csel[(size_t)(row0 + rr) * DS + 15] = acc;
    }
}

// ---------------------------------------------------------------- K3a: chunk-local scan (h from 0) -> chunk tail state + sum(delta)
// thread = one channel; h[16] in registers. grid (DI/256, PCH, G*BZ)
__global__ __launch_bounds__(256) void k3a_scanlocal(const u16* __restrict__ xcact,
        const float* __restrict__ delta, const float* __restrict__ bsel,
        const float* __restrict__ A_log, float* __restrict__ HST, float* __restrict__ SDLT)
{
    const int c  = blockIdx.x * 256 + threadIdx.x;
    const int j  = blockIdx.y;
    const int gb = blockIdx.z;
    const int g  = gb >> 2;
    float A_ls[16];
    {
        const float* ap = A_log + ((size_t)g * DI + c) * DS;
        #pragma unroll
        for (int s = 0; s < 16; ++s) A_ls[s] = -__expf(ap[s]);
    }
    float h[16];
    #pragma unroll
    for (int s = 0; s < 16; ++s) h[s] = 0.0f;
    float sdlt = 0.0f;
    const int rb = gb * LSEQ + j * CL;
    #pragma unroll 2
    for (int t = 0; t < CL; ++t){
        const int row = rb + t;
        const float dlt = delta[row];
        const float4 Bv0 = *(const float4*)&bsel[(size_t)row * DS + 0];
        const float4 Bv1 = *(const float4*)&bsel[(size_t)row * DS + 4];
        const float4 Bv2 = *(const float4*)&bsel[(size_t)row * DS + 8];
        const float4 Bv3 = *(const float4*)&bsel[(size_t)row * DS + 12];
        const float xv = bf2f(xcact[(size_t)row * DI + c]);
        const float bco = dlt * xv;
        float Bf[16] = {Bv0.x,Bv0.y,Bv0.z,Bv0.w, Bv1.x,Bv1.y,Bv1.z,Bv1.w,
                        Bv2.x,Bv2.y,Bv2.z,Bv2.w, Bv3.x,Bv3.y,Bv3.z,Bv3.w};
        sdlt += dlt;
        #pragma unroll
        for (int s = 0; s < 16; ++s){
            float q = __expf(dlt * A_ls[s]);
            h[s] = fmaf(q, h[s], bco * Bf[s]);
        }
    }
    const size_t base = ((size_t)(gb * PCH + j) * DS) * DI + c;
    #pragma unroll
    for (int s = 0; s < 16; ++s) HST[base + (size_t)s * DI] = h[s];
    if (blockIdx.x == 0 && threadIdx.x == 0) SDLT[gb * PCH + j] = sdlt;
}

// ---------------------------------------------------------------- K3b: chain chunk states; HST tail -> start (in place)
// thread = (gb, s, c); sequential over j
__global__ __launch_bounds__(256) void k3b_chain(float* __restrict__ HST,
        const float* __restrict__ SDLT, const float* __restrict__ A_log)
{
    const int idx = blockIdx.x * 256 + threadIdx.x;   // 16*16*1024
    const int c  = idx & 1023;
    const int s  = (idx >> 10) & 15;
    const int gb = idx >> 14;
    const int g  = gb >> 2;
    const float A_ls = -__expf(A_log[((size_t)g * DI + c) * DS + s]);
    float hc = 0.0f;
    #pragma unroll
    for (int j = 0; j < PCH; ++j){
        const float ap = __expf(A_ls * SDLT[gb * PCH + j]);
        const size_t off = ((size_t)(gb * PCH + j) * DS + s) * DI + c;
        const float tl = HST[off];
        HST[off] = hc;
        hc = fmaf(ap, hc, tl);
    }
}

// ---------------------------------------------------------------- K3c: re-run scan from correct h0, emit y*(gated) -> yg bf16
__global__ __launch_bounds__(256) void k3c_scanout(const u16* __restrict__ xcact,
        const u16* __restrict__ siluz, const float* __restrict__ delta,
        const float* __restrict__ bsel, const float* __restrict__ csel,
        const float* __restrict__ A_log, const float* __restrict__ Dp,
        const float* __restrict__ HST, u16* __restrict__ yg)
{
    const int c  = blockIdx.x * 256 + threadIdx.x;
    const int j  = blockIdx.y;
    const int gb = blockIdx.z;
    const int g  = gb >> 2;
    float A_ls[16];
    {
        const float* ap = A_log + ((size_t)g * DI + c) * DS;
        #pragma unroll
        for (int s = 0; s < 16; ++s) A_ls[s] = -__expf(ap[s]);
    }
    const float dpc = Dp[(size_t)g * DI + c];
    float h[16];
    {
        const size_t base = ((size_t)(gb * PCH + j) * DS) * DI + c;
        #pragma unroll
        for (int s = 0; s < 16; ++s) h[s] = HST[base + (size_t)s * DI];
    }
    const int rb = gb * LSEQ + j * CL;
    #pragma unroll 2
    for (int t = 0; t < CL; ++t){
        const int row = rb + t;
        const float dlt = delta[row];
        const float4 Bv0 = *(const float4*)&bsel[(size_t)row * DS + 0];
        const float4 Bv1 = *(const float4*)&bsel[(size_t)row * DS + 4];
        const float4 Bv2 = *(const float4*)&bsel[(size_t)row * DS + 8];
        const float4 Bv3 = *(const float4*)&bsel[(size_t)row * DS + 12];
        const float4 Cv0 = *(const float4*)&csel[(size_t)row * DS + 0];
        const float4 Cv1 = *(const float4*)&csel[(size_t)row * DS + 4];
        const float4 Cv2 = *(const float4*)&csel[(size_t)row * DS + 8];
        const float4 Cv3 = *(const float4*)&csel[(size_t)row * DS + 12];
        const float xv = bf2f(xcact[(size_t)row * DI + c]);
        const float zv = bf2f(siluz[(size_t)row * DI + c]);
        const float bco = dlt * xv;
        float Bf[16] = {Bv0.x,Bv0.y,Bv0.z,Bv0.w, Bv1.x,Bv1.y,Bv1.z,Bv1.w,
                        Bv2.x,Bv2.y,Bv2.z,Bv2.w, Bv3.x,Bv3.y,Bv3.z,Bv3.w};
        float Cf[16] = {Cv0.x,Cv0.y,Cv0.z,Cv0.w, Cv1.x,Cv1.y,Cv1.z,Cv1.w,
                        Cv2.x,Cv2.y,Cv2.z,Cv2.w, Cv3.x,Cv3.y,Cv3.z,Cv3.w};
        float y = 0.0f;
        #pragma unroll
        for (int s = 0; s < 16; ++s){
            float q = __expf(dlt * A_ls[s]);
            h[s] = fmaf(q, h[s], bco * Bf[s]);
            y = fmaf(h[s], Cf[s], y);
        }
        y = (y + xv * dpc) * zv;
        yg[(size_t)row * DI + c] = f2bf(y);
    }
}

// ---------------------------------------------------------------- K4: outs = yg @ out_w[g] via MFMA (fp32 out)
__global__ __launch_bounds__(256) void k4_mfma(const u16* __restrict__ YG,
        const u16* __restrict__ OUTWT, float* __restrict__ outs)
{
    __shared__ __align__(16) u16 As[128 * 32];
    __shared__ __align__(16) u16 Bs[128 * 32];
    const int g    = blockIdx.z;
    const int n0   = blockIdx.x * 128;
    const int row0 = blockIdx.y * 128;
    const int tid  = threadIdx.x;
    const int w = tid >> 6, lane = tid & 63;
    const int wr = w >> 1, wc = w & 1;
    const int srow = tid >> 2;
    const int kgrp = tid & 3;
    const u16* pA[2]; const u16* pB[2];
    #pragma unroll
    for (int i = 0; i < 2; ++i){
        pA[i] = YG    + ((size_t)(g * RB  + row0 + i * 64 + srow)) * DI + kgrp * 8;
        pB[i] = OUTWT + ((size_t)(g * DM  + n0   + i * 64 + srow)) * DI + kgrp * 8;
    }
    u16* ldsA = As + w * 512;
    u16* ldsB = Bs + w * 512;
    f32x4 acc[4][4];
    #pragma unroll
    for (int mi = 0; mi < 4; ++mi)
        #pragma unroll
        for (int ni = 0; ni < 4; ++ni)
            acc[mi][ni] = (f32x4){0.f, 0.f, 0.f, 0.f};
    const int ro = lane & 15;
    const int ko = (lane >> 4) * 8;
    for (int k0 = 0; k0 < DI; k0 += 32){
        gl2lds16(pA[0] + k0, ldsA);
        gl2lds16(pA[1] + k0, ldsA + 2048);
        gl2lds16(pB[0] + k0, ldsB);
        gl2lds16(pB[1] + k0, ldsB + 2048);
        __syncthreads();
        short8 af[4], bfr[4];
        #pragma unroll
        for (int mi = 0; mi < 4; ++mi)
            af[mi] = *(const short8*)&As[(wr * 64 + mi * 16 + ro) * 32 + ko];
        #pragma unroll
        for (int ni = 0; ni < 4; ++ni)
            bfr[ni] = *(const short8*)&Bs[(wc * 64 + ni * 16 + ro) * 32 + ko];
        #pragma unroll
        for (int mi = 0; mi < 4; ++mi)
            #pragma unroll
            for (int ni = 0; ni < 4; ++ni)
                acc[mi][ni] = __builtin_amdgcn_mfma_f32_16x16x32_bf16(af[mi], bfr[ni], acc[mi][ni], 0, 0, 0);
        __syncthreads();
    }
    const int colb = n0 + wc * 64 + (lane & 15);
    #pragma unroll
    for (int mi = 0; mi < 4; ++mi){
        #pragma unroll
        for (int rr = 0; rr < 4; ++rr){
            int r = row0 + wr * 64 + mi * 16 + (lane >> 4) * 4 + rr;
            size_t rowbase = ((size_t)g * RB + r) * DM;
            #pragma unroll
            for (int ni = 0; ni < 4; ++ni)
                outs[rowbase + colb + ni * 16] = acc[mi][ni][rr];
        }
    }
}

// ---------------------------------------------------------------- K5: combine + gate GEMM + residual + LayerNorm
__global__ __launch_bounds__(256) void k5_combine(const float* __restrict__ outs,
        const float* __restrict__ x, const float* __restrict__ gw, const float* __restrict__ gb,
        const float* __restrict__ lnw, const float* __restrict__ lnb, float* __restrict__ out)
{
    __shared__ float sh[8][512];
    __shared__ float sv[8][512];
    __shared__ float syb[8][512];
    const int tid = threadIdx.x;
    const int r0 = blockIdx.x * 8;
    const int b = r0 >> 11;
    for (int i = tid; i < 1024; i += 256){
        int rr = i >> 7, j4 = (i & 127) * 4;
        int l = (r0 + rr) & 2047, lf = 2047 - l;
        float4 o0 = *(const float4*)(outs + ((size_t)(0 * BZ + b) * LSEQ + l ) * DM + j4);
        float4 o1 = *(const float4*)(outs + ((size_t)(1 * BZ + b) * LSEQ + lf) * DM + j4);
        float4 o2 = *(const float4*)(outs + ((size_t)(2 * BZ + b) * LSEQ + l ) * DM + j4);
        float4 o3 = *(const float4*)(outs + ((size_t)(3 * BZ + b) * LSEQ + lf) * DM + j4);
        float4 hh, hv;
        hh.x = 0.5f * (o0.x + o1.x); hh.y = 0.5f * (o0.y + o1.y);
        hh.z = 0.5f * (o0.z + o1.z); hh.w = 0.5f * (o0.w + o1.w);
        hv.x = 0.5f * (o2.x + o3.x); hv.y = 0.5f * (o2.y + o3.y);
        hv.z = 0.5f * (o2.z + o3.z); hv.w = 0.5f * (o2.w + o3.w);
        *(float4*)&sh[rr][j4] = hh;
        *(float4*)&sv[rr][j4] = hv;
    }
    __syncthreads();
    float acc0[8] = {}, acc1[8] = {};
    const int j0 = tid, j1 = tid + 256;
    for (int k = 0; k < 512; ++k){
        float w0 = gw[(size_t)k * DM + j0];
        float w1 = gw[(size_t)k * DM + j1];
        #pragma unroll
        for (int rr = 0; rr < 8; ++rr){
            float hk = sh[rr][k];
            acc0[rr] = fmaf(hk, w0, acc0[rr]);
            acc1[rr] = fmaf(hk, w1, acc1[rr]);
        }
    }
    for (int k = 0; k < 512; ++k){
        float w0 = gw[(size_t)(k + 512) * DM + j0];
        float w1 = gw[(size_t)(k + 512) * DM + j1];
        #pragma unroll
        for (int rr = 0; rr < 8; ++rr){
            float hk = sv[rr][k];
            acc0[rr] = fmaf(hk, w0, acc0[rr]);
            acc1[rr] = fmaf(hk, w1, acc1[rr]);
        }
    }
    const float gb0 = gb[j0], gb1 = gb[j1];
    #pragma unroll
    for (int rr = 0; rr < 8; ++rr){
        int l = (r0 + rr) & 2047;
        size_t xbase = ((size_t)b * LSEQ + l) * DM;
        float g0 = sigmoidf_(acc0[rr] + gb0);
        float g1 = sigmoidf_(acc1[rr] + gb1);
        syb[rr][j0] = g0 * sh[rr][j0] + (1.0f - g0) * sv[rr][j0] + x[xbase + j0];
        syb[rr][j1] = g1 * sh[rr][j1] + (1.0f - g1) * sv[rr][j1] + x[xbase + j1];
    }
    __syncthreads();
    const int wv = tid >> 6, lane = tid & 63;
    for (int half = 0; half < 2; ++half){
        int rr = wv + half * 4;
        float sum = 0.0f, sq = 0.0f;
        #pragma unroll
        for (int i = 0; i < 8; ++i){
            float v = syb[rr][lane + i * 64];
            sum += v; sq = fmaf(v, v, sq);
        }
        #pragma unroll
        for (int m = 1; m < 64; m <<= 1){
            sum += __shfl_xor(sum, m);
            sq  += __shfl_xor(sq, m);
        }
        float mu = sum * (1.0f / 512.0f);
        float var = sq * (1.0f / 512.0f) - mu * mu;
        float rstd = rsqrtf(var + 1e-5f);
        int l = (r0 + rr) & 2047;
        size_t obase = ((size_t)b * LSEQ + l) * DM;
        #pragma unroll
        for (int i = 0; i < 8; ++i){
            int j = lane + i * 64;
            out[obase + j] = (syb[rr][j] - mu) * rstd * lnw[j] + lnb[j];
        }
    }
}

// ----------------------------------------------------------------
extern "C" void kernel_launch(void* const* d_in, const int* in_sizes, int n_in,
                              void* d_out, int out_size, void* d_ws, size_t ws_size,
                              hipStream_t stream)
{
    const float* x      = (const float*)d_in[0];
    const float* in_w   = (const float*)d_in[1];
    const float* conv_w = (const float*)d_in[2];
    const float* conv_b = (const float*)d_in[3];
    const float* xproj_w= (const float*)d_in[4];
    const float* A_log  = (const float*)d_in[5];
    const float* D_par  = (const float*)d_in[6];
    const float* out_w  = (const float*)d_in[7];
    const float* gate_w = (const float*)d_in[8];
    const float* gate_b = (const float*)d_in[9];
    const float* ln_w   = (const float*)d_in[10];
    const float* ln_b   = (const float*)d_in[11];
    float* out = (float*)d_out;

    char* ws = (char*)d_ws;
    u16* XCRAW = (u16*)(ws + 0);
    u16* SILUZ = (u16*)(ws + 67108864);
    u16* XCACT = (u16*)(ws + 134217728);
    float* DELTA = (float*)(ws + 201326592);   // 32768 f
    float* BSEL  = (float*)(ws + 201457664);   // 524288 f
    float* CSEL  = (float*)(ws + 203554816);   // 524288 f
    float* WT    = (float*)(ws + 205651968);   // 135168 f -> end 206192640
    u16*   INWT  = (u16*)(ws + 206192640);     // 8 MB; OUTWT aliases
    u16*   OUTWT = INWT;
    float* HST   = (float*)(ws + 214581248);   // 16 MB chunk states
    float* SDLT  = (float*)(ws + 231358464);   // 256 f
    u16*   XBF   = XCACT;                      // alias (XCACT written later by k2a)
    u16*   YG    = XCRAW;                      // alias (xcraw dead after k2a)
    float* OUTS  = (float*)(ws + 67108864);    // alias SILUZ (dead after k3c)

    p0_xbf<<<4096, 256, 0, stream>>>(x, XBF);
    pT<<<dim3(8, 32, G), 256, 0, stream>>>(in_w, INWT, DM, 2 * DI);
    k0_transpose_xproj<<<(G * 33 * DI + 255) / 256, 256, 0, stream>>>(xproj_w, WT);

    k1_mfma<<<dim3(16, 64, G), 256, 0, stream>>>(XBF, INWT, XCRAW, SILUZ);

    pT<<<dim3(16, 8, G), 256, 0, stream>>>(out_w, OUTWT, DI, DM);

    k2a_conv<<<(NROW * (DI / 4)) / 256, 256, 0, stream>>>(XCRAW, conv_w, conv_b, XCACT);

    k2b_xproj<<<NROW / 8, 256, 0, stream>>>(XCACT, WT, DELTA, BSEL, CSEL);

    dim3 g3(DI / 256, PCH, G * BZ);
    k3a_scanlocal<<<g3, 256, 0, stream>>>(XCACT, DELTA, BSEL, A_log, HST, SDLT);
    k3b_chain<<<(G * BZ * DS * DI) / 256, 256, 0, stream>>>(HST, SDLT, A_log);
    k3c_scanout<<<g3, 256, 0, stream>>>(XCACT, SILUZ, DELTA, BSEL, CSEL, A_log, D_par, HST, YG);

    k4_mfma<<<dim3(4, 64, G), 256, 0, stream>>>(YG, OUTWT, OUTS);

    k5_combine<<<RB / 8, 256, 0, stream>>>(OUTS, x, gate_w, gate_b, ln_w, ln_b, out);
}

// Round 4
// 696.545 us; speedup vs baseline: 3.9479x; 1.6250x over previous
//
#include <hip/hip_runtime.h>
#include <hip/hip_bf16.h>
#include <math.h>

#define G 4
#define BZ 4
#define LSEQ 2048
#define DM 512
#define DI 1024
#define DS 16
#define NROW (G*BZ*LSEQ)   /* 32768 */
#define RB (BZ*LSEQ)       /* 8192 rows per ssm-block */
#define PCH 16             /* scan chunks per sequence */
#define CL  (LSEQ/PCH)     /* 128 timesteps per chunk */

typedef unsigned short u16;
typedef unsigned int u32;

using short8 = __attribute__((ext_vector_type(8))) short;
using f32x4  = __attribute__((ext_vector_type(4))) float;

__device__ __forceinline__ float bf2f(u16 v){ return __uint_as_float(((u32)v) << 16); }
__device__ __forceinline__ u16 f2bf(float f){
    u32 u = __float_as_uint(f);
    u32 r = (u + 0x7FFFu + ((u >> 16) & 1u)) >> 16;   // RNE
    return (u16)r;
}
__device__ __forceinline__ float sigmoidf_(float x){ return 1.0f / (1.0f + __expf(-x)); }
__device__ __forceinline__ float siluf_(float x){ return x / (1.0f + __expf(-x)); }
__device__ __forceinline__ float softplusf_(float v){
    return fmaxf(v, 0.0f) + log1pf(__expf(-fabsf(v)));
}
__device__ __forceinline__ uint2 pack4bf(float a, float b, float c, float d){
    uint2 p;
    p.x = (u32)f2bf(a) | ((u32)f2bf(b) << 16);
    p.y = (u32)f2bf(c) | ((u32)f2bf(d) << 16);
    return p;
}
__device__ __forceinline__ void gl2lds16(const u16* g, u16* l){
    __builtin_amdgcn_global_load_lds(
        (const __attribute__((address_space(1))) u32*)g,
        (__attribute__((address_space(3))) u32*)l, 16, 0, 0);
}

// ---------------------------------------------------------------- P0: x fp32 -> bf16
__global__ void p0_xbf(const float* __restrict__ x, u16* __restrict__ xbf){
    size_t i = (size_t)(blockIdx.x * 256 + threadIdx.x) * 4;
    float4 v = *(const float4*)(x + i);
    *(uint2*)(xbf + i) = pack4bf(v.x, v.y, v.z, v.w);
}

// ---------------------------------------------------------------- PT: [g][R][C] fp32 -> [g][C][R] bf16 (tiled transpose)
__global__ __launch_bounds__(256) void pT(const float* __restrict__ in, u16* __restrict__ out,
                                          int R, int C){
    __shared__ float tl[64][65];
    const int g = blockIdx.z;
    const int r0 = blockIdx.x * 64, c0 = blockIdx.y * 64;
    const int t = threadIdx.x;
    #pragma unroll
    for (int p = 0; p < 4; ++p){
        int r = p * 16 + (t >> 4);
        int c = (t & 15) * 4;
        float4 v = *(const float4*)(in + ((size_t)g * R + r0 + r) * C + c0 + c);
        tl[r][c] = v.x; tl[r][c+1] = v.y; tl[r][c+2] = v.z; tl[r][c+3] = v.w;
    }
    __syncthreads();
    #pragma unroll
    for (int p = 0; p < 4; ++p){
        int oc = p * 16 + (t >> 4);
        int orr = (t & 15) * 4;
        uint2 pk = pack4bf(tl[orr][oc], tl[orr+1][oc], tl[orr+2][oc], tl[orr+3][oc]);
        *(uint2*)(out + ((size_t)g * C + c0 + oc) * R + r0 + orr) = pk;
    }
}

// ---------------------------------------------------------------- K0: xproj_w [g][d][33] -> WTB [g][48][1024] bf16 (padded B^T)
__global__ void k0_wtb(const float* __restrict__ xw, u16* __restrict__ wtb){
    int i = blockIdx.x * 256 + threadIdx.x;    // G*48*1024
    if (i >= G * 48 * 1024) return;
    int d  = i & 1023;
    int go = i >> 10;
    int o  = go % 48;
    int g  = go / 48;
    float v = (o < 33) ? xw[((size_t)g * DI + d) * 33 + o] : 0.0f;
    wtb[i] = f2bf(v);
}

// ---------------------------------------------------------------- K1: xz = Xin[g] @ in_w[g] via MFMA; split -> xcraw(bf16), silu(z)(bf16)
__global__ __launch_bounds__(256) void k1_mfma(const u16* __restrict__ XBF,
        const u16* __restrict__ INWT, u16* __restrict__ xcraw, u16* __restrict__ siluz)
{
    __shared__ __align__(16) u16 As[128 * 32];
    __shared__ __align__(16) u16 Bs[128 * 32];
    const int g    = blockIdx.z;
    const int n0   = blockIdx.x * 128;
    const int row0 = blockIdx.y * 128;
    const int tid  = threadIdx.x;
    const int w = tid >> 6, lane = tid & 63;
    const int wr = w >> 1, wc = w & 1;
    const int srow = tid >> 2;     // 0..63
    const int kgrp = tid & 3;
    const u16* pA[2]; const u16* pB[2];
    #pragma unroll
    for (int i = 0; i < 2; ++i){
        int r = row0 + i * 64 + srow;
        int b = r >> 11, l = r & 2047;
        int lsrc = (g & 1) ? (2047 - l) : l;
        pA[i] = XBF  + ((size_t)((b << 11) + lsrc)) * DM + kgrp * 8;
        pB[i] = INWT + ((size_t)(g * 2048 + n0 + i * 64 + srow)) * DM + kgrp * 8;
    }
    u16* ldsA = As + w * 512;
    u16* ldsB = Bs + w * 512;
    f32x4 acc[4][4];
    #pragma unroll
    for (int mi = 0; mi < 4; ++mi)
        #pragma unroll
        for (int ni = 0; ni < 4; ++ni)
            acc[mi][ni] = (f32x4){0.f, 0.f, 0.f, 0.f};
    const int ro = lane & 15;
    const int ko = (lane >> 4) * 8;
    for (int k0 = 0; k0 < DM; k0 += 32){
        gl2lds16(pA[0] + k0, ldsA);
        gl2lds16(pA[1] + k0, ldsA + 2048);
        gl2lds16(pB[0] + k0, ldsB);
        gl2lds16(pB[1] + k0, ldsB + 2048);
        __syncthreads();
        short8 af[4], bfr[4];
        #pragma unroll
        for (int mi = 0; mi < 4; ++mi)
            af[mi] = *(const short8*)&As[(wr * 64 + mi * 16 + ro) * 32 + ko];
        #pragma unroll
        for (int ni = 0; ni < 4; ++ni)
            bfr[ni] = *(const short8*)&Bs[(wc * 64 + ni * 16 + ro) * 32 + ko];
        #pragma unroll
        for (int mi = 0; mi < 4; ++mi)
            #pragma unroll
            for (int ni = 0; ni < 4; ++ni)
                acc[mi][ni] = __builtin_amdgcn_mfma_f32_16x16x32_bf16(af[mi], bfr[ni], acc[mi][ni], 0, 0, 0);
        __syncthreads();
    }
    const bool is_z = (n0 >= DI);
    u16* outp = is_z ? siluz : xcraw;
    const int colb = n0 - (is_z ? DI : 0) + wc * 64 + (lane & 15);
    #pragma unroll
    for (int mi = 0; mi < 4; ++mi){
        #pragma unroll
        for (int rr = 0; rr < 4; ++rr){
            int r = row0 + wr * 64 + mi * 16 + (lane >> 4) * 4 + rr;
            int b = r >> 11, l = r & 2047;
            size_t rowbase = ((size_t)(g * BZ + b) * LSEQ + l) * DI;
            #pragma unroll
            for (int ni = 0; ni < 4; ++ni){
                float v = acc[mi][ni][rr];
                if (is_z) v = siluf_(v);
                outp[rowbase + colb + ni * 16] = f2bf(v);
            }
        }
    }
}

// ---------------------------------------------------------------- K2a: depthwise causal conv(4) + bias + silu
__global__ __launch_bounds__(256) void k2a_conv(const u16* __restrict__ xcraw,
        const float* __restrict__ cw, const float* __restrict__ cb, u16* __restrict__ xcact)
{
    int idx = blockIdx.x * 256 + threadIdx.x;
    int c4   = (idx & 255) * 4;
    int grow = idx >> 8;
    int l = grow & 2047;
    int g = grow >> 13;
    size_t rowbase = (size_t)grow * DI + c4;
    float v[4][4];
    #pragma unroll
    for (int t = 0; t < 4; ++t){
        int lt = l - 3 + t;
        if (lt >= 0){
            uint2 p = *(const uint2*)(xcraw + rowbase + (size_t)(t - 3) * DI);
            v[t][0] = bf2f((u16)(p.x & 0xffff)); v[t][1] = bf2f((u16)(p.x >> 16));
            v[t][2] = bf2f((u16)(p.y & 0xffff)); v[t][3] = bf2f((u16)(p.y >> 16));
        } else {
            v[t][0] = v[t][1] = v[t][2] = v[t][3] = 0.0f;
        }
    }
    const float* wc = cw + ((size_t)g * DI + c4) * 4;
    float4 w0 = *(const float4*)(wc + 0);
    float4 w1 = *(const float4*)(wc + 4);
    float4 w2 = *(const float4*)(wc + 8);
    float4 w3 = *(const float4*)(wc + 12);
    float4 bias = *(const float4*)(cb + (size_t)g * DI + c4);
    float wj[4][4] = {{w0.x,w0.y,w0.z,w0.w},{w1.x,w1.y,w1.z,w1.w},
                      {w2.x,w2.y,w2.z,w2.w},{w3.x,w3.y,w3.z,w3.w}};
    float bj[4] = {bias.x, bias.y, bias.z, bias.w};
    float o[4];
    #pragma unroll
    for (int j = 0; j < 4; ++j){
        float s = bj[j];
        #pragma unroll
        for (int t = 0; t < 4; ++t) s = fmaf(wj[j][t], v[t][j], s);
        o[j] = siluf_(s);
    }
    *(uint2*)(xcact + rowbase) = pack4bf(o[0], o[1], o[2], o[3]);
}

// ---------------------------------------------------------------- K2b (MFMA): xp = xc @ xproj_w -> delta(softplus), B, C
// A = xcact [32768][1024] bf16; B^T = WTB [g][48][1024] bf16 (rows 33..47 zero)
__global__ __launch_bounds__(256) void k2b_mfma(const u16* __restrict__ xcact,
        const u16* __restrict__ wtb, float* __restrict__ delta,
        float* __restrict__ bsel, float* __restrict__ csel)
{
    __shared__ __align__(16) u16 As[64 * 32];   // 4 KB
    __shared__ __align__(16) u16 Bs[48 * 32];   // 3 KB
    const int row0 = blockIdx.x * 64;
    const int g = row0 >> 13;
    const int tid = threadIdx.x;
    const int w = tid >> 6, lane = tid & 63;
    const int srow = tid >> 2;       // 0..63
    const int kgrp = tid & 3;
    const u16* pA = xcact + (size_t)(row0 + srow) * DI + kgrp * 8;
    const u16* pB = wtb + ((size_t)g * 48 + srow) * DI + kgrp * 8;   // valid tid<192
    u16* ldsA = As + w * 512;
    u16* ldsB = Bs + w * 512;
    f32x4 acc[3];
    #pragma unroll
    for (int t = 0; t < 3; ++t) acc[t] = (f32x4){0.f, 0.f, 0.f, 0.f};
    const int ro = lane & 15;
    const int ko = (lane >> 4) * 8;
    for (int k0 = 0; k0 < DI; k0 += 32){
        gl2lds16(pA + k0, ldsA);
        if (w < 3) gl2lds16(pB + k0, ldsB);
        __syncthreads();
        short8 af = *(const short8*)&As[(w * 16 + ro) * 32 + ko];
        #pragma unroll
        for (int t = 0; t < 3; ++t){
            short8 bf = *(const short8*)&Bs[(t * 16 + ro) * 32 + ko];
            acc[t] = __builtin_amdgcn_mfma_f32_16x16x32_bf16(af, bf, acc[t], 0, 0, 0);
        }
        __syncthreads();
    }
    // C layout: o = t*16 + (lane&15); row = w*16 + (lane>>4)*4 + rr
    #pragma unroll
    for (int t = 0; t < 3; ++t){
        const int o = t * 16 + (lane & 15);
        #pragma unroll
        for (int rr = 0; rr < 4; ++rr){
            const int r = row0 + w * 16 + (lane >> 4) * 4 + rr;
            const float v = acc[t][rr];
            if (o == 0)       delta[r] = softplusf_(v);
            else if (o < 17)  bsel[(size_t)r * DS + (o - 1)]  = v;
            else if (o < 33)  csel[(size_t)r * DS + (o - 17)] = v;
        }
    }
}

// ---------------------------------------------------------------- K3a: chunk-local scan (h from 0) -> chunk tail state + sum(delta)
__global__ __launch_bounds__(256) void k3a_scanlocal(const u16* __restrict__ xcact,
        const float* __restrict__ delta, const float* __restrict__ bsel,
        const float* __restrict__ A_log, float* __restrict__ HST, float* __restrict__ SDLT)
{
    const int c  = blockIdx.x * 256 + threadIdx.x;
    const int j  = blockIdx.y;
    const int gb = blockIdx.z;
    const int g  = gb >> 2;
    float A_ls[16];
    {
        const float* ap = A_log + ((size_t)g * DI + c) * DS;
        #pragma unroll
        for (int s = 0; s < 16; ++s) A_ls[s] = -__expf(ap[s]);
    }
    float h[16];
    #pragma unroll
    for (int s = 0; s < 16; ++s) h[s] = 0.0f;
    float sdlt = 0.0f;
    const int rb = gb * LSEQ + j * CL;
    #pragma unroll 2
    for (int t = 0; t < CL; ++t){
        const int row = rb + t;
        const float dlt = delta[row];
        const float4 Bv0 = *(const float4*)&bsel[(size_t)row * DS + 0];
        const float4 Bv1 = *(const float4*)&bsel[(size_t)row * DS + 4];
        const float4 Bv2 = *(const float4*)&bsel[(size_t)row * DS + 8];
        const float4 Bv3 = *(const float4*)&bsel[(size_t)row * DS + 12];
        const float xv = bf2f(xcact[(size_t)row * DI + c]);
        const float bco = dlt * xv;
        float Bf[16] = {Bv0.x,Bv0.y,Bv0.z,Bv0.w, Bv1.x,Bv1.y,Bv1.z,Bv1.w,
                        Bv2.x,Bv2.y,Bv2.z,Bv2.w, Bv3.x,Bv3.y,Bv3.z,Bv3.w};
        sdlt += dlt;
        #pragma unroll
        for (int s = 0; s < 16; ++s){
            float q = __expf(dlt * A_ls[s]);
            h[s] = fmaf(q, h[s], bco * Bf[s]);
        }
    }
    const size_t base = ((size_t)(gb * PCH + j) * DS) * DI + c;
    #pragma unroll
    for (int s = 0; s < 16; ++s) HST[base + (size_t)s * DI] = h[s];
    if (blockIdx.x == 0 && threadIdx.x == 0) SDLT[gb * PCH + j] = sdlt;
}

// ---------------------------------------------------------------- K3b: chain chunk states; HST tail -> start (in place)
__global__ __launch_bounds__(256) void k3b_chain(float* __restrict__ HST,
        const float* __restrict__ SDLT, const float* __restrict__ A_log)
{
    const int idx = blockIdx.x * 256 + threadIdx.x;   // 16*16*1024
    const int c  = idx & 1023;
    const int s  = (idx >> 10) & 15;
    const int gb = idx >> 14;
    const int g  = gb >> 2;
    const float A_ls = -__expf(A_log[((size_t)g * DI + c) * DS + s]);
    float hc = 0.0f;
    #pragma unroll
    for (int j = 0; j < PCH; ++j){
        const float ap = __expf(A_ls * SDLT[gb * PCH + j]);
        const size_t off = ((size_t)(gb * PCH + j) * DS + s) * DI + c;
        const float tl = HST[off];
        HST[off] = hc;
        hc = fmaf(ap, hc, tl);
    }
}

// ---------------------------------------------------------------- K3c: re-run scan from correct h0, emit y*(gated) -> yg bf16
__global__ __launch_bounds__(256) void k3c_scanout(const u16* __restrict__ xcact,
        const u16* __restrict__ siluz, const float* __restrict__ delta,
        const float* __restrict__ bsel, const float* __restrict__ csel,
        const float* __restrict__ A_log, const float* __restrict__ Dp,
        const float* __restrict__ HST, u16* __restrict__ yg)
{
    const int c  = blockIdx.x * 256 + threadIdx.x;
    const int j  = blockIdx.y;
    const int gb = blockIdx.z;
    const int g  = gb >> 2;
    float A_ls[16];
    {
        const float* ap = A_log + ((size_t)g * DI + c) * DS;
        #pragma unroll
        for (int s = 0; s < 16; ++s) A_ls[s] = -__expf(ap[s]);
    }
    const float dpc = Dp[(size_t)g * DI + c];
    float h[16];
    {
        const size_t base = ((size_t)(gb * PCH + j) * DS) * DI + c;
        #pragma unroll
        for (int s = 0; s < 16; ++s) h[s] = HST[base + (size_t)s * DI];
    }
    const int rb = gb * LSEQ + j * CL;
    #pragma unroll 2
    for (int t = 0; t < CL; ++t){
        const int row = rb + t;
        const float dlt = delta[row];
        const float4 Bv0 = *(const float4*)&bsel[(size_t)row * DS + 0];
        const float4 Bv1 = *(const float4*)&bsel[(size_t)row * DS + 4];
        const float4 Bv2 = *(const float4*)&bsel[(size_t)row * DS + 8];
        const float4 Bv3 = *(const float4*)&bsel[(size_t)row * DS + 12];
        const float4 Cv0 = *(const float4*)&csel[(size_t)row * DS + 0];
        const float4 Cv1 = *(const float4*)&csel[(size_t)row * DS + 4];
        const float4 Cv2 = *(const float4*)&csel[(size_t)row * DS + 8];
        const float4 Cv3 = *(const float4*)&csel[(size_t)row * DS + 12];
        const float xv = bf2f(xcact[(size_t)row * DI + c]);
        const float zv = bf2f(siluz[(size_t)row * DI + c]);
        const float bco = dlt * xv;
        float Bf[16] = {Bv0.x,Bv0.y,Bv0.z,Bv0.w, Bv1.x,Bv1.y,Bv1.z,Bv1.w,
                        Bv2.x,Bv2.y,Bv2.z,Bv2.w, Bv3.x,Bv3.y,Bv3.z,Bv3.w};
        float Cf[16] = {Cv0.x,Cv0.y,Cv0.z,Cv0.w, Cv1.x,Cv1.y,Cv1.z,Cv1.w,
                        Cv2.x,Cv2.y,Cv2.z,Cv2.w, Cv3.x,Cv3.y,Cv3.z,Cv3.w};
        float y = 0.0f;
        #pragma unroll
        for (int s = 0; s < 16; ++s){
            float q = __expf(dlt * A_ls[s]);
            h[s] = fmaf(q, h[s], bco * Bf[s]);
            y = fmaf(h[s], Cf[s], y);
        }
        y = (y + xv * dpc) * zv;
        yg[(size_t)row * DI + c] = f2bf(y);
    }
}

// ---------------------------------------------------------------- K4: outs = yg @ out_w[g] via MFMA (fp32 out)
__global__ __launch_bounds__(256) void k4_mfma(const u16* __restrict__ YG,
        const u16* __restrict__ OUTWT, float* __restrict__ outs)
{
    __shared__ __align__(16) u16 As[128 * 32];
    __shared__ __align__(16) u16 Bs[128 * 32];
    const int g    = blockIdx.z;
    const int n0   = blockIdx.x * 128;
    const int row0 = blockIdx.y * 128;
    const int tid  = threadIdx.x;
    const int w = tid >> 6, lane = tid & 63;
    const int wr = w >> 1, wc = w & 1;
    const int srow = tid >> 2;
    const int kgrp = tid & 3;
    const u16* pA[2]; const u16* pB[2];
    #pragma unroll
    for (int i = 0; i < 2; ++i){
        pA[i] = YG    + ((size_t)(g * RB  + row0 + i * 64 + srow)) * DI + kgrp * 8;
        pB[i] = OUTWT + ((size_t)(g * DM  + n0   + i * 64 + srow)) * DI + kgrp * 8;
    }
    u16* ldsA = As + w * 512;
    u16* ldsB = Bs + w * 512;
    f32x4 acc[4][4];
    #pragma unroll
    for (int mi = 0; mi < 4; ++mi)
        #pragma unroll
        for (int ni = 0; ni < 4; ++ni)
            acc[mi][ni] = (f32x4){0.f, 0.f, 0.f, 0.f};
    const int ro = lane & 15;
    const int ko = (lane >> 4) * 8;
    for (int k0 = 0; k0 < DI; k0 += 32){
        gl2lds16(pA[0] + k0, ldsA);
        gl2lds16(pA[1] + k0, ldsA + 2048);
        gl2lds16(pB[0] + k0, ldsB);
        gl2lds16(pB[1] + k0, ldsB + 2048);
        __syncthreads();
        short8 af[4], bfr[4];
        #pragma unroll
        for (int mi = 0; mi < 4; ++mi)
            af[mi] = *(const short8*)&As[(wr * 64 + mi * 16 + ro) * 32 + ko];
        #pragma unroll
        for (int ni = 0; ni < 4; ++ni)
            bfr[ni] = *(const short8*)&Bs[(wc * 64 + ni * 16 + ro) * 32 + ko];
        #pragma unroll
        for (int mi = 0; mi < 4; ++mi)
            #pragma unroll
            for (int ni = 0; ni < 4; ++ni)
                acc[mi][ni] = __builtin_amdgcn_mfma_f32_16x16x32_bf16(af[mi], bfr[ni], acc[mi][ni], 0, 0, 0);
        __syncthreads();
    }
    const int colb = n0 + wc * 64 + (lane & 15);
    #pragma unroll
    for (int mi = 0; mi < 4; ++mi){
        #pragma unroll
        for (int rr = 0; rr < 4; ++rr){
            int r = row0 + wr * 64 + mi * 16 + (lane >> 4) * 4 + rr;
            size_t rowbase = ((size_t)g * RB + r) * DM;
            #pragma unroll
            for (int ni = 0; ni < 4; ++ni)
                outs[rowbase + colb + ni * 16] = acc[mi][ni][rr];
        }
    }
}

// ---------------------------------------------------------------- K5: combine + gate GEMM + residual + LayerNorm
__global__ __launch_bounds__(256) void k5_combine(const float* __restrict__ outs,
        const float* __restrict__ x, const float* __restrict__ gw, const float* __restrict__ gb,
        const float* __restrict__ lnw, const float* __restrict__ lnb, float* __restrict__ out)
{
    __shared__ float sh[8][512];
    __shared__ float sv[8][512];
    __shared__ float syb[8][512];
    const int tid = threadIdx.x;
    const int r0 = blockIdx.x * 8;
    const int b = r0 >> 11;
    for (int i = tid; i < 1024; i += 256){
        int rr = i >> 7, j4 = (i & 127) * 4;
        int l = (r0 + rr) & 2047, lf = 2047 - l;
        float4 o0 = *(const float4*)(outs + ((size_t)(0 * BZ + b) * LSEQ + l ) * DM + j4);
        float4 o1 = *(const float4*)(outs + ((size_t)(1 * BZ + b) * LSEQ + lf) * DM + j4);
        float4 o2 = *(const float4*)(outs + ((size_t)(2 * BZ + b) * LSEQ + l ) * DM + j4);
        float4 o3 = *(const float4*)(outs + ((size_t)(3 * BZ + b) * LSEQ + lf) * DM + j4);
        float4 hh, hv;
        hh.x = 0.5f * (o0.x + o1.x); hh.y = 0.5f * (o0.y + o1.y);
        hh.z = 0.5f * (o0.z + o1.z); hh.w = 0.5f * (o0.w + o1.w);
        hv.x = 0.5f * (o2.x + o3.x); hv.y = 0.5f * (o2.y + o3.y);
        hv.z = 0.5f * (o2.z + o3.z); hv.w = 0.5f * (o2.w + o3.w);
        *(float4*)&sh[rr][j4] = hh;
        *(float4*)&sv[rr][j4] = hv;
    }
    __syncthreads();
    float acc0[8] = {}, acc1[8] = {};
    const int j0 = tid, j1 = tid + 256;
    for (int k = 0; k < 512; ++k){
        float w0 = gw[(size_t)k * DM + j0];
        float w1 = gw[(size_t)k * DM + j1];
        #pragma unroll
        for (int rr = 0; rr < 8; ++rr){
            float hk = sh[rr][k];
            acc0[rr] = fmaf(hk, w0, acc0[rr]);
            acc1[rr] = fmaf(hk, w1, acc1[rr]);
        }
    }
    for (int k = 0; k < 512; ++k){
        float w0 = gw[(size_t)(k + 512) * DM + j0];
        float w1 = gw[(size_t)(k + 512) * DM + j1];
        #pragma unroll
        for (int rr = 0; rr < 8; ++rr){
            float hk = sv[rr][k];
            acc0[rr] = fmaf(hk, w0, acc0[rr]);
            acc1[rr] = fmaf(hk, w1, acc1[rr]);
        }
    }
    const float gb0 = gb[j0], gb1 = gb[j1];
    #pragma unroll
    for (int rr = 0; rr < 8; ++rr){
        int l = (r0 + rr) & 2047;
        size_t xbase = ((size_t)b * LSEQ + l) * DM;
        float g0 = sigmoidf_(acc0[rr] + gb0);
        float g1 = sigmoidf_(acc1[rr] + gb1);
        syb[rr][j0] = g0 * sh[rr][j0] + (1.0f - g0) * sv[rr][j0] + x[xbase + j0];
        syb[rr][j1] = g1 * sh[rr][j1] + (1.0f - g1) * sv[rr][j1] + x[xbase + j1];
    }
    __syncthreads();
    const int wv = tid >> 6, lane = tid & 63;
    for (int half = 0; half < 2; ++half){
        int rr = wv + half * 4;
        float sum = 0.0f, sq = 0.0f;
        #pragma unroll
        for (int i = 0; i < 8; ++i){
            float v = syb[rr][lane + i * 64];
            sum += v; sq = fmaf(v, v, sq);
        }
        #pragma unroll
        for (int m = 1; m < 64; m <<= 1){
            sum += __shfl_xor(sum, m);
            sq  += __shfl_xor(sq, m);
        }
        float mu = sum * (1.0f / 512.0f);
        float var = sq * (1.0f / 512.0f) - mu * mu;
        float rstd = rsqrtf(var + 1e-5f);
        int l = (r0 + rr) & 2047;
        size_t obase = ((size_t)b * LSEQ + l) * DM;
        #pragma unroll
        for (int i = 0; i < 8; ++i){
            int j = lane + i * 64;
            out[obase + j] = (syb[rr][j] - mu) * rstd * lnw[j] + lnb[j];
        }
    }
}

// ----------------------------------------------------------------
extern "C" void kernel_launch(void* const* d_in, const int* in_sizes, int n_in,
                              void* d_out, int out_size, void* d_ws, size_t ws_size,
                              hipStream_t stream)
{
    const float* x      = (const float*)d_in[0];
    const float* in_w   = (const float*)d_in[1];
    const float* conv_w = (const float*)d_in[2];
    const float* conv_b = (const float*)d_in[3];
    const float* xproj_w= (const float*)d_in[4];
    const float* A_log  = (const float*)d_in[5];
    const float* D_par  = (const float*)d_in[6];
    const float* out_w  = (const float*)d_in[7];
    const float* gate_w = (const float*)d_in[8];
    const float* gate_b = (const float*)d_in[9];
    const float* ln_w   = (const float*)d_in[10];
    const float* ln_b   = (const float*)d_in[11];
    float* out = (float*)d_out;

    char* ws = (char*)d_ws;
    u16* XCRAW = (u16*)(ws + 0);
    u16* SILUZ = (u16*)(ws + 67108864);
    u16* XCACT = (u16*)(ws + 134217728);
    float* DELTA = (float*)(ws + 201326592);   // 32768 f
    float* BSEL  = (float*)(ws + 201457664);   // 524288 f
    float* CSEL  = (float*)(ws + 203554816);   // 524288 f
    u16*   WTB   = (u16*)(ws + 205651968);     // G*48*1024 bf16 = 393216 B
    u16*   INWT  = (u16*)(ws + 206192640);     // 8 MB; OUTWT aliases
    u16*   OUTWT = INWT;
    float* HST   = (float*)(ws + 214581248);   // 16 MB chunk states
    float* SDLT  = (float*)(ws + 231358464);   // 256 f
    u16*   XBF   = XCACT;                      // alias (XCACT written later by k2a)
    u16*   YG    = XCRAW;                      // alias (xcraw dead after k2a)
    float* OUTS  = (float*)(ws + 67108864);    // alias SILUZ (dead after k3c)

    p0_xbf<<<4096, 256, 0, stream>>>(x, XBF);
    pT<<<dim3(8, 32, G), 256, 0, stream>>>(in_w, INWT, DM, 2 * DI);
    k0_wtb<<<(G * 48 * 1024 + 255) / 256, 256, 0, stream>>>(xproj_w, WTB);

    k1_mfma<<<dim3(16, 64, G), 256, 0, stream>>>(XBF, INWT, XCRAW, SILUZ);

    pT<<<dim3(16, 8, G), 256, 0, stream>>>(out_w, OUTWT, DI, DM);

    k2a_conv<<<(NROW * (DI / 4)) / 256, 256, 0, stream>>>(XCRAW, conv_w, conv_b, XCACT);

    k2b_mfma<<<NROW / 64, 256, 0, stream>>>(XCACT, WTB, DELTA, BSEL, CSEL);

    dim3 g3(DI / 256, PCH, G * BZ);
    k3a_scanlocal<<<g3, 256, 0, stream>>>(XCACT, DELTA, BSEL, A_log, HST, SDLT);
    k3b_chain<<<(G * BZ * DS * DI) / 256, 256, 0, stream>>>(HST, SDLT, A_log);
    k3c_scanout<<<g3, 256, 0, stream>>>(XCACT, SILUZ, DELTA, BSEL, CSEL, A_log, D_par, HST, YG);

    k4_mfma<<<dim3(4, 64, G), 256, 0, stream>>>(YG, OUTWT, OUTS);

    k5_combine<<<RB / 8, 256, 0, stream>>>(OUTS, x, gate_w, gate_b, ln_w, ln_b, out);
}

// Round 5
// 568.659 us; speedup vs baseline: 4.8357x; 1.2249x over previous
//
#include <hip/hip_runtime.h>
#include <hip/hip_bf16.h>
#include <math.h>

#define G 4
#define BZ 4
#define LSEQ 2048
#define DM 512
#define DI 1024
#define DS 16
#define NROW (G*BZ*LSEQ)   /* 32768 */
#define RB (BZ*LSEQ)       /* 8192 rows per ssm-block */
#define PCH 16             /* scan chunks per sequence */
#define CL  (LSEQ/PCH)     /* 128 timesteps per chunk */

typedef unsigned short u16;
typedef unsigned int u32;

using short8 = __attribute__((ext_vector_type(8))) short;
using f32x4  = __attribute__((ext_vector_type(4))) float;

__device__ __forceinline__ float bf2f(u16 v){ return __uint_as_float(((u32)v) << 16); }
__device__ __forceinline__ u16 f2bf(float f){
    u32 u = __float_as_uint(f);
    u32 r = (u + 0x7FFFu + ((u >> 16) & 1u)) >> 16;   // RNE
    return (u16)r;
}
__device__ __forceinline__ float sigmoidf_(float x){ return 1.0f / (1.0f + __expf(-x)); }
__device__ __forceinline__ float siluf_(float x){ return x / (1.0f + __expf(-x)); }
__device__ __forceinline__ float softplusf_(float v){
    return fmaxf(v, 0.0f) + log1pf(__expf(-fabsf(v)));
}
__device__ __forceinline__ uint2 pack4bf(float a, float b, float c, float d){
    uint2 p;
    p.x = (u32)f2bf(a) | ((u32)f2bf(b) << 16);
    p.y = (u32)f2bf(c) | ((u32)f2bf(d) << 16);
    return p;
}
__device__ __forceinline__ void gl2lds16(const u16* g, u16* l){
    __builtin_amdgcn_global_load_lds(
        (const __attribute__((address_space(1))) u32*)g,
        (__attribute__((address_space(3))) u32*)l, 16, 0, 0);
}

// ---------------------------------------------------------------- P0: x fp32 -> bf16
__global__ void p0_xbf(const float* __restrict__ x, u16* __restrict__ xbf){
    size_t i = (size_t)(blockIdx.x * 256 + threadIdx.x) * 4;
    float4 v = *(const float4*)(x + i);
    *(uint2*)(xbf + i) = pack4bf(v.x, v.y, v.z, v.w);
}

// ---------------------------------------------------------------- PT: [g][R][C] fp32 -> [g][C][R] bf16 (tiled transpose)
__global__ __launch_bounds__(256) void pT(const float* __restrict__ in, u16* __restrict__ out,
                                          int R, int C){
    __shared__ float tl[64][65];
    const int g = blockIdx.z;
    const int r0 = blockIdx.x * 64, c0 = blockIdx.y * 64;
    const int t = threadIdx.x;
    #pragma unroll
    for (int p = 0; p < 4; ++p){
        int r = p * 16 + (t >> 4);
        int c = (t & 15) * 4;
        float4 v = *(const float4*)(in + ((size_t)g * R + r0 + r) * C + c0 + c);
        tl[r][c] = v.x; tl[r][c+1] = v.y; tl[r][c+2] = v.z; tl[r][c+3] = v.w;
    }
    __syncthreads();
    #pragma unroll
    for (int p = 0; p < 4; ++p){
        int oc = p * 16 + (t >> 4);
        int orr = (t & 15) * 4;
        uint2 pk = pack4bf(tl[orr][oc], tl[orr+1][oc], tl[orr+2][oc], tl[orr+3][oc]);
        *(uint2*)(out + ((size_t)g * C + c0 + oc) * R + r0 + orr) = pk;
    }
}

// ---------------------------------------------------------------- K0: xproj_w [g][d][33] -> WTB [g][48][1024] bf16 (padded B^T)
__global__ void k0_wtb(const float* __restrict__ xw, u16* __restrict__ wtb){
    int i = blockIdx.x * 256 + threadIdx.x;    // G*48*1024
    if (i >= G * 48 * 1024) return;
    int d  = i & 1023;
    int go = i >> 10;
    int o  = go % 48;
    int g  = go / 48;
    float v = (o < 33) ? xw[((size_t)g * DI + d) * 33 + o] : 0.0f;
    wtb[i] = f2bf(v);
}

// ---------------------------------------------------------------- K1: xz = Xin[g] @ in_w[g] via MFMA; split -> xcraw(bf16), silu(z)(bf16)
__global__ __launch_bounds__(256) void k1_mfma(const u16* __restrict__ XBF,
        const u16* __restrict__ INWT, u16* __restrict__ xcraw, u16* __restrict__ siluz)
{
    __shared__ __align__(16) u16 As[128 * 32];
    __shared__ __align__(16) u16 Bs[128 * 32];
    const int g    = blockIdx.z;
    const int n0   = blockIdx.x * 128;
    const int row0 = blockIdx.y * 128;
    const int tid  = threadIdx.x;
    const int w = tid >> 6, lane = tid & 63;
    const int wr = w >> 1, wc = w & 1;
    const int srow = tid >> 2;     // 0..63
    const int kgrp = tid & 3;
    const u16* pA[2]; const u16* pB[2];
    #pragma unroll
    for (int i = 0; i < 2; ++i){
        int r = row0 + i * 64 + srow;
        int b = r >> 11, l = r & 2047;
        int lsrc = (g & 1) ? (2047 - l) : l;
        pA[i] = XBF  + ((size_t)((b << 11) + lsrc)) * DM + kgrp * 8;
        pB[i] = INWT + ((size_t)(g * 2048 + n0 + i * 64 + srow)) * DM + kgrp * 8;
    }
    u16* ldsA = As + w * 512;
    u16* ldsB = Bs + w * 512;
    f32x4 acc[4][4];
    #pragma unroll
    for (int mi = 0; mi < 4; ++mi)
        #pragma unroll
        for (int ni = 0; ni < 4; ++ni)
            acc[mi][ni] = (f32x4){0.f, 0.f, 0.f, 0.f};
    const int ro = lane & 15;
    const int ko = (lane >> 4) * 8;
    for (int k0 = 0; k0 < DM; k0 += 32){
        gl2lds16(pA[0] + k0, ldsA);
        gl2lds16(pA[1] + k0, ldsA + 2048);
        gl2lds16(pB[0] + k0, ldsB);
        gl2lds16(pB[1] + k0, ldsB + 2048);
        __syncthreads();
        short8 af[4], bfr[4];
        #pragma unroll
        for (int mi = 0; mi < 4; ++mi)
            af[mi] = *(const short8*)&As[(wr * 64 + mi * 16 + ro) * 32 + ko];
        #pragma unroll
        for (int ni = 0; ni < 4; ++ni)
            bfr[ni] = *(const short8*)&Bs[(wc * 64 + ni * 16 + ro) * 32 + ko];
        #pragma unroll
        for (int mi = 0; mi < 4; ++mi)
            #pragma unroll
            for (int ni = 0; ni < 4; ++ni)
                acc[mi][ni] = __builtin_amdgcn_mfma_f32_16x16x32_bf16(af[mi], bfr[ni], acc[mi][ni], 0, 0, 0);
        __syncthreads();
    }
    const bool is_z = (n0 >= DI);
    u16* outp = is_z ? siluz : xcraw;
    const int colb = n0 - (is_z ? DI : 0) + wc * 64 + (lane & 15);
    #pragma unroll
    for (int mi = 0; mi < 4; ++mi){
        #pragma unroll
        for (int rr = 0; rr < 4; ++rr){
            int r = row0 + wr * 64 + mi * 16 + (lane >> 4) * 4 + rr;
            int b = r >> 11, l = r & 2047;
            size_t rowbase = ((size_t)(g * BZ + b) * LSEQ + l) * DI;
            #pragma unroll
            for (int ni = 0; ni < 4; ++ni){
                float v = acc[mi][ni][rr];
                if (is_z) v = siluf_(v);
                outp[rowbase + colb + ni * 16] = f2bf(v);
            }
        }
    }
}

// ---------------------------------------------------------------- K2a: depthwise causal conv(4) + bias + silu
__global__ __launch_bounds__(256) void k2a_conv(const u16* __restrict__ xcraw,
        const float* __restrict__ cw, const float* __restrict__ cb, u16* __restrict__ xcact)
{
    int idx = blockIdx.x * 256 + threadIdx.x;
    int c4   = (idx & 255) * 4;
    int grow = idx >> 8;
    int l = grow & 2047;
    int g = grow >> 13;
    size_t rowbase = (size_t)grow * DI + c4;
    float v[4][4];
    #pragma unroll
    for (int t = 0; t < 4; ++t){
        int lt = l - 3 + t;
        if (lt >= 0){
            uint2 p = *(const uint2*)(xcraw + rowbase + (size_t)(t - 3) * DI);
            v[t][0] = bf2f((u16)(p.x & 0xffff)); v[t][1] = bf2f((u16)(p.x >> 16));
            v[t][2] = bf2f((u16)(p.y & 0xffff)); v[t][3] = bf2f((u16)(p.y >> 16));
        } else {
            v[t][0] = v[t][1] = v[t][2] = v[t][3] = 0.0f;
        }
    }
    const float* wc = cw + ((size_t)g * DI + c4) * 4;
    float4 w0 = *(const float4*)(wc + 0);
    float4 w1 = *(const float4*)(wc + 4);
    float4 w2 = *(const float4*)(wc + 8);
    float4 w3 = *(const float4*)(wc + 12);
    float4 bias = *(const float4*)(cb + (size_t)g * DI + c4);
    float wj[4][4] = {{w0.x,w0.y,w0.z,w0.w},{w1.x,w1.y,w1.z,w1.w},
                      {w2.x,w2.y,w2.z,w2.w},{w3.x,w3.y,w3.z,w3.w}};
    float bj[4] = {bias.x, bias.y, bias.z, bias.w};
    float o[4];
    #pragma unroll
    for (int j = 0; j < 4; ++j){
        float s = bj[j];
        #pragma unroll
        for (int t = 0; t < 4; ++t) s = fmaf(wj[j][t], v[t][j], s);
        o[j] = siluf_(s);
    }
    *(uint2*)(xcact + rowbase) = pack4bf(o[0], o[1], o[2], o[3]);
}

// ---------------------------------------------------------------- K2b (MFMA): xp = xc @ xproj_w -> delta(softplus), B, C
__global__ __launch_bounds__(256) void k2b_mfma(const u16* __restrict__ xcact,
        const u16* __restrict__ wtb, float* __restrict__ delta,
        float* __restrict__ bsel, float* __restrict__ csel)
{
    __shared__ __align__(16) u16 As[64 * 32];   // 4 KB
    __shared__ __align__(16) u16 Bs[48 * 32];   // 3 KB
    const int row0 = blockIdx.x * 64;
    const int g = row0 >> 13;
    const int tid = threadIdx.x;
    const int w = tid >> 6, lane = tid & 63;
    const int srow = tid >> 2;       // 0..63
    const int kgrp = tid & 3;
    const u16* pA = xcact + (size_t)(row0 + srow) * DI + kgrp * 8;
    const u16* pB = wtb + ((size_t)g * 48 + srow) * DI + kgrp * 8;   // valid tid<192
    u16* ldsA = As + w * 512;
    u16* ldsB = Bs + w * 512;
    f32x4 acc[3];
    #pragma unroll
    for (int t = 0; t < 3; ++t) acc[t] = (f32x4){0.f, 0.f, 0.f, 0.f};
    const int ro = lane & 15;
    const int ko = (lane >> 4) * 8;
    for (int k0 = 0; k0 < DI; k0 += 32){
        gl2lds16(pA + k0, ldsA);
        if (w < 3) gl2lds16(pB + k0, ldsB);
        __syncthreads();
        short8 af = *(const short8*)&As[(w * 16 + ro) * 32 + ko];
        #pragma unroll
        for (int t = 0; t < 3; ++t){
            short8 bf = *(const short8*)&Bs[(t * 16 + ro) * 32 + ko];
            acc[t] = __builtin_amdgcn_mfma_f32_16x16x32_bf16(af, bf, acc[t], 0, 0, 0);
        }
        __syncthreads();
    }
    #pragma unroll
    for (int t = 0; t < 3; ++t){
        const int o = t * 16 + (lane & 15);
        #pragma unroll
        for (int rr = 0; rr < 4; ++rr){
            const int r = row0 + w * 16 + (lane >> 4) * 4 + rr;
            const float v = acc[t][rr];
            if (o == 0)       delta[r] = softplusf_(v);
            else if (o < 17)  bsel[(size_t)r * DS + (o - 1)]  = v;
            else if (o < 33)  csel[(size_t)r * DS + (o - 17)] = v;
        }
    }
}

// ---------------------------------------------------------------- K3a: chunk-local scan (h from 0) -> chunk tail state + sum(delta)
__global__ __launch_bounds__(256) void k3a_scanlocal(const u16* __restrict__ xcact,
        const float* __restrict__ delta, const float* __restrict__ bsel,
        const float* __restrict__ A_log, float* __restrict__ HST, float* __restrict__ SDLT)
{
    const int c  = blockIdx.x * 256 + threadIdx.x;
    const int j  = blockIdx.y;
    const int gb = blockIdx.z;
    const int g  = gb >> 2;
    float A_ls[16];
    {
        const float* ap = A_log + ((size_t)g * DI + c) * DS;
        #pragma unroll
        for (int s = 0; s < 16; ++s) A_ls[s] = -__expf(ap[s]);
    }
    float h[16];
    #pragma unroll
    for (int s = 0; s < 16; ++s) h[s] = 0.0f;
    float sdlt = 0.0f;
    const int rb = gb * LSEQ + j * CL;
    #pragma unroll 2
    for (int t = 0; t < CL; ++t){
        const int row = rb + t;
        const float dlt = delta[row];
        const float4 Bv0 = *(const float4*)&bsel[(size_t)row * DS + 0];
        const float4 Bv1 = *(const float4*)&bsel[(size_t)row * DS + 4];
        const float4 Bv2 = *(const float4*)&bsel[(size_t)row * DS + 8];
        const float4 Bv3 = *(const float4*)&bsel[(size_t)row * DS + 12];
        const float xv = bf2f(xcact[(size_t)row * DI + c]);
        const float bco = dlt * xv;
        float Bf[16] = {Bv0.x,Bv0.y,Bv0.z,Bv0.w, Bv1.x,Bv1.y,Bv1.z,Bv1.w,
                        Bv2.x,Bv2.y,Bv2.z,Bv2.w, Bv3.x,Bv3.y,Bv3.z,Bv3.w};
        sdlt += dlt;
        #pragma unroll
        for (int s = 0; s < 16; ++s){
            float q = __expf(dlt * A_ls[s]);
            h[s] = fmaf(q, h[s], bco * Bf[s]);
        }
    }
    const size_t base = ((size_t)(gb * PCH + j) * DS) * DI + c;
    #pragma unroll
    for (int s = 0; s < 16; ++s) HST[base + (size_t)s * DI] = h[s];
    if (blockIdx.x == 0 && threadIdx.x == 0) SDLT[gb * PCH + j] = sdlt;
}

// ---------------------------------------------------------------- K3b: chain chunk states; HST tail -> start (in place)
__global__ __launch_bounds__(256) void k3b_chain(float* __restrict__ HST,
        const float* __restrict__ SDLT, const float* __restrict__ A_log)
{
    const int idx = blockIdx.x * 256 + threadIdx.x;   // 16*16*1024
    const int c  = idx & 1023;
    const int s  = (idx >> 10) & 15;
    const int gb = idx >> 14;
    const int g  = gb >> 2;
    const float A_ls = -__expf(A_log[((size_t)g * DI + c) * DS + s]);
    float hc = 0.0f;
    #pragma unroll
    for (int j = 0; j < PCH; ++j){
        const float ap = __expf(A_ls * SDLT[gb * PCH + j]);
        const size_t off = ((size_t)(gb * PCH + j) * DS + s) * DI + c;
        const float tl = HST[off];
        HST[off] = hc;
        hc = fmaf(ap, hc, tl);
    }
}

// ---------------------------------------------------------------- K3c: re-run scan from correct h0, emit y*(gated) -> yg bf16
__global__ __launch_bounds__(256) void k3c_scanout(const u16* __restrict__ xcact,
        const u16* __restrict__ siluz, const float* __restrict__ delta,
        const float* __restrict__ bsel, const float* __restrict__ csel,
        const float* __restrict__ A_log, const float* __restrict__ Dp,
        const float* __restrict__ HST, u16* __restrict__ yg)
{
    const int c  = blockIdx.x * 256 + threadIdx.x;
    const int j  = blockIdx.y;
    const int gb = blockIdx.z;
    const int g  = gb >> 2;
    float A_ls[16];
    {
        const float* ap = A_log + ((size_t)g * DI + c) * DS;
        #pragma unroll
        for (int s = 0; s < 16; ++s) A_ls[s] = -__expf(ap[s]);
    }
    const float dpc = Dp[(size_t)g * DI + c];
    float h[16];
    {
        const size_t base = ((size_t)(gb * PCH + j) * DS) * DI + c;
        #pragma unroll
        for (int s = 0; s < 16; ++s) h[s] = HST[base + (size_t)s * DI];
    }
    const int rb = gb * LSEQ + j * CL;
    #pragma unroll 2
    for (int t = 0; t < CL; ++t){
        const int row = rb + t;
        const float dlt = delta[row];
        const float4 Bv0 = *(const float4*)&bsel[(size_t)row * DS + 0];
        const float4 Bv1 = *(const float4*)&bsel[(size_t)row * DS + 4];
        const float4 Bv2 = *(const float4*)&bsel[(size_t)row * DS + 8];
        const float4 Bv3 = *(const float4*)&bsel[(size_t)row * DS + 12];
        const float4 Cv0 = *(const float4*)&csel[(size_t)row * DS + 0];
        const float4 Cv1 = *(const float4*)&csel[(size_t)row * DS + 4];
        const float4 Cv2 = *(const float4*)&csel[(size_t)row * DS + 8];
        const float4 Cv3 = *(const float4*)&csel[(size_t)row * DS + 12];
        const float xv = bf2f(xcact[(size_t)row * DI + c]);
        const float zv = bf2f(siluz[(size_t)row * DI + c]);
        const float bco = dlt * xv;
        float Bf[16] = {Bv0.x,Bv0.y,Bv0.z,Bv0.w, Bv1.x,Bv1.y,Bv1.z,Bv1.w,
                        Bv2.x,Bv2.y,Bv2.z,Bv2.w, Bv3.x,Bv3.y,Bv3.z,Bv3.w};
        float Cf[16] = {Cv0.x,Cv0.y,Cv0.z,Cv0.w, Cv1.x,Cv1.y,Cv1.z,Cv1.w,
                        Cv2.x,Cv2.y,Cv2.z,Cv2.w, Cv3.x,Cv3.y,Cv3.z,Cv3.w};
        float y = 0.0f;
        #pragma unroll
        for (int s = 0; s < 16; ++s){
            float q = __expf(dlt * A_ls[s]);
            h[s] = fmaf(q, h[s], bco * Bf[s]);
            y = fmaf(h[s], Cf[s], y);
        }
        y = (y + xv * dpc) * zv;
        yg[(size_t)row * DI + c] = f2bf(y);
    }
}

// ---------------------------------------------------------------- K4: outs = yg @ out_w[g] via MFMA (fp32 out)
__global__ __launch_bounds__(256) void k4_mfma(const u16* __restrict__ YG,
        const u16* __restrict__ OUTWT, float* __restrict__ outs)
{
    __shared__ __align__(16) u16 As[128 * 32];
    __shared__ __align__(16) u16 Bs[128 * 32];
    const int g    = blockIdx.z;
    const int n0   = blockIdx.x * 128;
    const int row0 = blockIdx.y * 128;
    const int tid  = threadIdx.x;
    const int w = tid >> 6, lane = tid & 63;
    const int wr = w >> 1, wc = w & 1;
    const int srow = tid >> 2;
    const int kgrp = tid & 3;
    const u16* pA[2]; const u16* pB[2];
    #pragma unroll
    for (int i = 0; i < 2; ++i){
        pA[i] = YG    + ((size_t)(g * RB  + row0 + i * 64 + srow)) * DI + kgrp * 8;
        pB[i] = OUTWT + ((size_t)(g * DM  + n0   + i * 64 + srow)) * DI + kgrp * 8;
    }
    u16* ldsA = As + w * 512;
    u16* ldsB = Bs + w * 512;
    f32x4 acc[4][4];
    #pragma unroll
    for (int mi = 0; mi < 4; ++mi)
        #pragma unroll
        for (int ni = 0; ni < 4; ++ni)
            acc[mi][ni] = (f32x4){0.f, 0.f, 0.f, 0.f};
    const int ro = lane & 15;
    const int ko = (lane >> 4) * 8;
    for (int k0 = 0; k0 < DI; k0 += 32){
        gl2lds16(pA[0] + k0, ldsA);
        gl2lds16(pA[1] + k0, ldsA + 2048);
        gl2lds16(pB[0] + k0, ldsB);
        gl2lds16(pB[1] + k0, ldsB + 2048);
        __syncthreads();
        short8 af[4], bfr[4];
        #pragma unroll
        for (int mi = 0; mi < 4; ++mi)
            af[mi] = *(const short8*)&As[(wr * 64 + mi * 16 + ro) * 32 + ko];
        #pragma unroll
        for (int ni = 0; ni < 4; ++ni)
            bfr[ni] = *(const short8*)&Bs[(wc * 64 + ni * 16 + ro) * 32 + ko];
        #pragma unroll
        for (int mi = 0; mi < 4; ++mi)
            #pragma unroll
            for (int ni = 0; ni < 4; ++ni)
                acc[mi][ni] = __builtin_amdgcn_mfma_f32_16x16x32_bf16(af[mi], bfr[ni], acc[mi][ni], 0, 0, 0);
        __syncthreads();
    }
    const int colb = n0 + wc * 64 + (lane & 15);
    #pragma unroll
    for (int mi = 0; mi < 4; ++mi){
        #pragma unroll
        for (int rr = 0; rr < 4; ++rr){
            int r = row0 + wr * 64 + mi * 16 + (lane >> 4) * 4 + rr;
            size_t rowbase = ((size_t)g * RB + r) * DM;
            #pragma unroll
            for (int ni = 0; ni < 4; ++ni)
                outs[rowbase + colb + ni * 16] = acc[mi][ni][rr];
        }
    }
}

// ---------------------------------------------------------------- K4b: combine 4 planes -> HH,HV fp32 + HHVB bf16 [8192][1024]
__global__ __launch_bounds__(256) void k4b_combine(const float* __restrict__ outs,
        float* __restrict__ HH, float* __restrict__ HV, u16* __restrict__ HHVB)
{
    const int idx = blockIdx.x * 256 + threadIdx.x;   // 8192*128
    const int j4  = (idx & 127) * 4;
    const int row = idx >> 7;                          // b*2048 + l
    const int b = row >> 11, l = row & 2047, lf = 2047 - l;
    float4 o0 = *(const float4*)(outs + ((size_t)(0 * BZ + b) * LSEQ + l ) * DM + j4);
    float4 o1 = *(const float4*)(outs + ((size_t)(1 * BZ + b) * LSEQ + lf) * DM + j4);
    float4 o2 = *(const float4*)(outs + ((size_t)(2 * BZ + b) * LSEQ + l ) * DM + j4);
    float4 o3 = *(const float4*)(outs + ((size_t)(3 * BZ + b) * LSEQ + lf) * DM + j4);
    float4 hh, hv;
    hh.x = 0.5f * (o0.x + o1.x); hh.y = 0.5f * (o0.y + o1.y);
    hh.z = 0.5f * (o0.z + o1.z); hh.w = 0.5f * (o0.w + o1.w);
    hv.x = 0.5f * (o2.x + o3.x); hv.y = 0.5f * (o2.y + o3.y);
    hv.z = 0.5f * (o2.z + o3.z); hv.w = 0.5f * (o2.w + o3.w);
    const size_t base = (size_t)row * DM + j4;
    *(float4*)(HH + base) = hh;
    *(float4*)(HV + base) = hv;
    const size_t bb = (size_t)row * (2 * DM) + j4;
    *(uint2*)(HHVB + bb)      = pack4bf(hh.x, hh.y, hh.z, hh.w);
    *(uint2*)(HHVB + bb + DM) = pack4bf(hv.x, hv.y, hv.z, hv.w);
}

// ---------------------------------------------------------------- K5 (MFMA): gate logits = HHVB @ gate_w
// A = HHVB [8192][1024] bf16, B^T = GWT [512][1024] bf16
__global__ __launch_bounds__(256) void k5_mfma(const u16* __restrict__ HHVB,
        const u16* __restrict__ GWT, float* __restrict__ GL)
{
    __shared__ __align__(16) u16 As[128 * 32];
    __shared__ __align__(16) u16 Bs[128 * 32];
    const int n0   = blockIdx.x * 128;
    const int row0 = blockIdx.y * 128;
    const int tid  = threadIdx.x;
    const int w = tid >> 6, lane = tid & 63;
    const int wr = w >> 1, wc = w & 1;
    const int srow = tid >> 2;
    const int kgrp = tid & 3;
    const u16* pA[2]; const u16* pB[2];
    #pragma unroll
    for (int i = 0; i < 2; ++i){
        pA[i] = HHVB + ((size_t)(row0 + i * 64 + srow)) * (2 * DM) + kgrp * 8;
        pB[i] = GWT  + ((size_t)(n0   + i * 64 + srow)) * (2 * DM) + kgrp * 8;
    }
    u16* ldsA = As + w * 512;
    u16* ldsB = Bs + w * 512;
    f32x4 acc[4][4];
    #pragma unroll
    for (int mi = 0; mi < 4; ++mi)
        #pragma unroll
        for (int ni = 0; ni < 4; ++ni)
            acc[mi][ni] = (f32x4){0.f, 0.f, 0.f, 0.f};
    const int ro = lane & 15;
    const int ko = (lane >> 4) * 8;
    for (int k0 = 0; k0 < 2 * DM; k0 += 32){
        gl2lds16(pA[0] + k0, ldsA);
        gl2lds16(pA[1] + k0, ldsA + 2048);
        gl2lds16(pB[0] + k0, ldsB);
        gl2lds16(pB[1] + k0, ldsB + 2048);
        __syncthreads();
        short8 af[4], bfr[4];
        #pragma unroll
        for (int mi = 0; mi < 4; ++mi)
            af[mi] = *(const short8*)&As[(wr * 64 + mi * 16 + ro) * 32 + ko];
        #pragma unroll
        for (int ni = 0; ni < 4; ++ni)
            bfr[ni] = *(const short8*)&Bs[(wc * 64 + ni * 16 + ro) * 32 + ko];
        #pragma unroll
        for (int mi = 0; mi < 4; ++mi)
            #pragma unroll
            for (int ni = 0; ni < 4; ++ni)
                acc[mi][ni] = __builtin_amdgcn_mfma_f32_16x16x32_bf16(af[mi], bfr[ni], acc[mi][ni], 0, 0, 0);
        __syncthreads();
    }
    const int colb = n0 + wc * 64 + (lane & 15);
    #pragma unroll
    for (int mi = 0; mi < 4; ++mi){
        #pragma unroll
        for (int rr = 0; rr < 4; ++rr){
            int r = row0 + wr * 64 + mi * 16 + (lane >> 4) * 4 + rr;
            size_t rowbase = (size_t)r * DM;
            #pragma unroll
            for (int ni = 0; ni < 4; ++ni)
                GL[rowbase + colb + ni * 16] = acc[mi][ni][rr];
        }
    }
}

// ---------------------------------------------------------------- K6: gate + residual + LayerNorm (vector, no LDS)
__global__ __launch_bounds__(256) void k6_gateln(const float* __restrict__ GL,
        const float* __restrict__ HH, const float* __restrict__ HV,
        const float* __restrict__ x, const float* __restrict__ gb,
        const float* __restrict__ lnw, const float* __restrict__ lnb, float* __restrict__ out)
{
    const int tid = threadIdx.x;
    const int r0 = blockIdx.x * 8;
    const int w = tid >> 6, lane = tid & 63;
    const int j0 = lane * 8;
    float4 gbv0 = *(const float4*)(gb + j0),  gbv1 = *(const float4*)(gb + j0 + 4);
    float4 lw0  = *(const float4*)(lnw + j0), lw1  = *(const float4*)(lnw + j0 + 4);
    float4 lb0  = *(const float4*)(lnb + j0), lb1  = *(const float4*)(lnb + j0 + 4);
    float gba[8] = {gbv0.x,gbv0.y,gbv0.z,gbv0.w, gbv1.x,gbv1.y,gbv1.z,gbv1.w};
    float lwa[8] = {lw0.x,lw0.y,lw0.z,lw0.w, lw1.x,lw1.y,lw1.z,lw1.w};
    float lba[8] = {lb0.x,lb0.y,lb0.z,lb0.w, lb1.x,lb1.y,lb1.z,lb1.w};
    #pragma unroll
    for (int half = 0; half < 2; ++half){
        const int row = r0 + w + half * 4;
        const size_t base = (size_t)row * DM + j0;
        float4 gl0 = *(const float4*)(GL + base), gl1 = *(const float4*)(GL + base + 4);
        float4 hh0 = *(const float4*)(HH + base), hh1 = *(const float4*)(HH + base + 4);
        float4 hv0 = *(const float4*)(HV + base), hv1 = *(const float4*)(HV + base + 4);
        float4 xx0 = *(const float4*)(x + base),  xx1 = *(const float4*)(x + base + 4);
        float gla[8] = {gl0.x,gl0.y,gl0.z,gl0.w, gl1.x,gl1.y,gl1.z,gl1.w};
        float hha[8] = {hh0.x,hh0.y,hh0.z,hh0.w, hh1.x,hh1.y,hh1.z,hh1.w};
        float hva[8] = {hv0.x,hv0.y,hv0.z,hv0.w, hv1.x,hv1.y,hv1.z,hv1.w};
        float xxa[8] = {xx0.x,xx0.y,xx0.z,xx0.w, xx1.x,xx1.y,xx1.z,xx1.w};
        float y[8];
        float sum = 0.0f, sq = 0.0f;
        #pragma unroll
        for (int i = 0; i < 8; ++i){
            float gv = sigmoidf_(gla[i] + gba[i]);
            float v = gv * hha[i] + (1.0f - gv) * hva[i] + xxa[i];
            y[i] = v;
            sum += v; sq = fmaf(v, v, sq);
        }
        #pragma unroll
        for (int m = 1; m < 64; m <<= 1){
            sum += __shfl_xor(sum, m);
            sq  += __shfl_xor(sq, m);
        }
        float mu = sum * (1.0f / 512.0f);
        float var = sq * (1.0f / 512.0f) - mu * mu;
        float rstd = rsqrtf(var + 1e-5f);
        float o[8];
        #pragma unroll
        for (int i = 0; i < 8; ++i)
            o[i] = (y[i] - mu) * rstd * lwa[i] + lba[i];
        *(float4*)(out + base)     = (float4){o[0], o[1], o[2], o[3]};
        *(float4*)(out + base + 4) = (float4){o[4], o[5], o[6], o[7]};
    }
}

// ----------------------------------------------------------------
extern "C" void kernel_launch(void* const* d_in, const int* in_sizes, int n_in,
                              void* d_out, int out_size, void* d_ws, size_t ws_size,
                              hipStream_t stream)
{
    const float* x      = (const float*)d_in[0];
    const float* in_w   = (const float*)d_in[1];
    const float* conv_w = (const float*)d_in[2];
    const float* conv_b = (const float*)d_in[3];
    const float* xproj_w= (const float*)d_in[4];
    const float* A_log  = (const float*)d_in[5];
    const float* D_par  = (const float*)d_in[6];
    const float* out_w  = (const float*)d_in[7];
    const float* gate_w = (const float*)d_in[8];
    const float* gate_b = (const float*)d_in[9];
    const float* ln_w   = (const float*)d_in[10];
    const float* ln_b   = (const float*)d_in[11];
    float* out = (float*)d_out;

    char* ws = (char*)d_ws;
    u16* XCRAW = (u16*)(ws + 0);
    u16* SILUZ = (u16*)(ws + 67108864);
    u16* XCACT = (u16*)(ws + 134217728);
    float* DELTA = (float*)(ws + 201326592);   // 32768 f
    float* BSEL  = (float*)(ws + 201457664);   // 524288 f
    float* CSEL  = (float*)(ws + 203554816);   // 524288 f
    u16*   WTB   = (u16*)(ws + 205651968);     // 393216 B
    u16*   INWT  = (u16*)(ws + 206192640);     // 8 MB; OUTWT & GWT alias (sequenced)
    u16*   OUTWT = INWT;
    u16*   GWT   = INWT;                       // written after k4 (OUTWT dead)
    float* HST   = (float*)(ws + 214581248);   // 16 MB chunk states
    float* SDLT  = (float*)(ws + 231358464);   // 256 f
    u16*   XBF   = XCACT;                      // alias (XCACT written later by k2a)
    u16*   YG    = XCRAW;                      // alias (xcraw dead after k2a)
    float* OUTS  = (float*)(ws + 67108864);    // alias SILUZ (dead after k3c)
    // XCACT region (64 MB) reused after k3c/k4:
    float* HH    = (float*)(ws + 134217728);   // 16 MB
    float* HV    = (float*)(ws + 150994944);   // 16 MB
    u16*   HHVB  = (u16*)(ws + 167772160);     // 16 MB
    float* GL    = OUTS;                       // alias (OUTS dead after k4b)

    p0_xbf<<<4096, 256, 0, stream>>>(x, XBF);
    pT<<<dim3(8, 32, G), 256, 0, stream>>>(in_w, INWT, DM, 2 * DI);
    k0_wtb<<<(G * 48 * 1024 + 255) / 256, 256, 0, stream>>>(xproj_w, WTB);

    k1_mfma<<<dim3(16, 64, G), 256, 0, stream>>>(XBF, INWT, XCRAW, SILUZ);

    pT<<<dim3(16, 8, G), 256, 0, stream>>>(out_w, OUTWT, DI, DM);

    k2a_conv<<<(NROW * (DI / 4)) / 256, 256, 0, stream>>>(XCRAW, conv_w, conv_b, XCACT);

    k2b_mfma<<<NROW / 64, 256, 0, stream>>>(XCACT, WTB, DELTA, BSEL, CSEL);

    dim3 g3(DI / 256, PCH, G * BZ);
    k3a_scanlocal<<<g3, 256, 0, stream>>>(XCACT, DELTA, BSEL, A_log, HST, SDLT);
    k3b_chain<<<(G * BZ * DS * DI) / 256, 256, 0, stream>>>(HST, SDLT, A_log);
    k3c_scanout<<<g3, 256, 0, stream>>>(XCACT, SILUZ, DELTA, BSEL, CSEL, A_log, D_par, HST, YG);

    k4_mfma<<<dim3(4, 64, G), 256, 0, stream>>>(YG, OUTWT, OUTS);

    // gate_w transpose into dead INWT region (after k4 consumed OUTWT)
    pT<<<dim3(16, 8, 1), 256, 0, stream>>>(gate_w, GWT, 2 * DM, DM);

    k4b_combine<<<RB * (DM / 4) / 256, 256, 0, stream>>>(OUTS, HH, HV, HHVB);

    k5_mfma<<<dim3(4, 64, 1), 256, 0, stream>>>(HHVB, GWT, GL);

    k6_gateln<<<RB / 8, 256, 0, stream>>>(GL, HH, HV, x, gate_b, ln_w, ln_b, out);
}